// Round 7
// baseline (3525.243 us; speedup 1.0000x reference)
//
#include <hip/hip_runtime.h>
#include <math.h>

#define SLEN 64
#define BATCH 256
#define VIND 128
#define VOUTD 128
#define UDIM 1024
#define EDIM 512
#define TDEC 25
#define GXW 1536
#define U3 3072
#define NSEG 12

typedef __attribute__((ext_vector_type(8))) short short8;
typedef __attribute__((ext_vector_type(4))) float f32x4;

#define MFMA(acc, A, B) acc = __builtin_amdgcn_mfma_f32_16x16x32_bf16((A), (B), (acc), 0, 0, 0)

// libm sigmoid/tanh in the RECURRENT path (gates): fast variants drift over the
// 64-step encoder + 24-step decoder recurrence and flip greedy argmax (R1 fail).
__device__ __forceinline__ float sigm(float x) { return 1.f / (1.f + expf(-x)); }

// fast tanh for the attention SCORE path only (non-recurrent-critical)
__device__ __forceinline__ float tanhf_fast(float x) {
    float ax = fabsf(x);
    float e = __expf(-2.f * ax);
    float t = (1.f - e) / (1.f + e);
    return copysignf(t, x);
}

__device__ __forceinline__ short f2bf(float f) {
    unsigned u = __float_as_uint(f);
    u += 0x7FFF + ((u >> 16) & 1);
    return (short)(u >> 16);
}
__device__ __forceinline__ float bf2f(short h) {
    return __uint_as_float(((unsigned)(unsigned short)h) << 16);
}

// fragment-major packed layout for operand X[R][K]:
// chunk(r,k) holds X[r][k..k+8); lane = (r&15) + 16*((k>>3)&3)
__device__ __forceinline__ size_t pkChunk(int r, int k, int K) {
    return ((size_t)(r >> 4) * (K >> 5) + (k >> 5)) * 64 + ((r & 15) + 16 * ((k >> 3) & 3));
}

union S8 { short s[8]; short8 v; };

__device__ __forceinline__ void writeSplit8(short* Hi, short* Lo, size_t chunk,
                                            const float* vals) {
    S8 h, l;
#pragma unroll
    for (int j = 0; j < 8; j++) {
        short hb = f2bf(vals[j]);
        h.s[j] = hb;
        l.s[j] = f2bf(vals[j] - bf2f(hb));
    }
    ((short8*)Hi)[chunk] = h.v;
    ((short8*)Lo)[chunk] = l.v;
}

// ---------------------------------------------------------------------------
__global__ void init_kernel(float* __restrict__ h0, short* __restrict__ hpHi,
                            short* __restrict__ hpLo, float* __restrict__ out0,
                            int* __restrict__ idx,
                            const float* __restrict__ o2h_W,
                            const float* __restrict__ o2h_b,
                            float* __restrict__ o2hT) {
    int i = blockIdx.x * 256 + threadIdx.x;
    if (i < BATCH * UDIM) { h0[i] = 0.f; hpHi[i] = 0; hpLo[i] = 0; }
    if (i < BATCH * VOUTD) out0[i] = ((i & (VOUTD - 1)) == 0) ? 1.f : 0.f;
    if (i < BATCH) idx[i] = 0;
    if (i < VOUTD * EDIM) {
        // o2hT[v][e] = o2h_W[e][v] + o2h_b[e]  (bias folded, row-read at decode)
        int v = i >> 9, e = i & (EDIM - 1);
        o2hT[i] = o2h_W[(size_t)e * VOUTD + v] + o2h_b[e];
    }
}

// ---------------------------------------------------------------------------
// All weight/input packing in ONE kernel: segment table passed by value.
// ---------------------------------------------------------------------------
struct PackSeg {
    const float* sA; const float* sB;
    short* Hi; short* Lo;
    int KA, KB, offA, offB, chunkStart;
};
struct PackArgs { PackSeg s[NSEG]; };

__global__ void pack_all(PackArgs pa, int total) {
    int gid = blockIdx.x * 256 + threadIdx.x;
    if (gid >= total) return;
    int si = 0;
#pragma unroll
    for (int i = 1; i < NSEG; i++) si = (gid >= pa.s[i].chunkStart) ? i : si;
    PackSeg sg = pa.s[si];
    int local = gid - sg.chunkStart;
    int K = sg.KA + sg.KB;
    int cpr = K >> 3;
    int r = local / cpr, k0 = (local - r * cpr) * 8;
    const float* src = (k0 < sg.KA)
        ? sg.sA + (size_t)(sg.offA + r) * sg.KA + k0
        : sg.sB + (size_t)(sg.offB + r) * sg.KB + (k0 - sg.KA);
    float v[8];
#pragma unroll
    for (int j = 0; j < 8; j++) v[j] = src[j];
    writeSplit8(sg.Hi, sg.Lo, pkChunk(r, k0, K), v);
}

// ---------------------------------------------------------------------------
// Split-bf16 3-pass MFMA GEMM, BM=64 x BN=128 block (4 waves of 32x64).
// ---------------------------------------------------------------------------
__global__ __launch_bounds__(256) void gemm_w(
    const short8* __restrict__ Ahi, const short8* __restrict__ Alo,
    const short8* __restrict__ Whi, const short8* __restrict__ Wlo,
    const float* __restrict__ bias, float* __restrict__ C,
    int KT, int N) {
    int tid = threadIdx.x, lane = tid & 63, wave = tid >> 6;
    int m16 = blockIdx.x * 4 + (wave & 1) * 2;
    int nb = blockIdx.y * 8 + (wave >> 1) * 4;
    const short8* a0h = Ahi + (size_t)m16 * KT * 64 + lane;
    const short8* a1h = a0h + (size_t)KT * 64;
    const short8* a0l = Alo + (size_t)m16 * KT * 64 + lane;
    const short8* a1l = a0l + (size_t)KT * 64;
    const short8* w0h = Whi + (size_t)(nb + 0) * KT * 64 + lane;
    const short8* w1h = Whi + (size_t)(nb + 1) * KT * 64 + lane;
    const short8* w2h = Whi + (size_t)(nb + 2) * KT * 64 + lane;
    const short8* w3h = Whi + (size_t)(nb + 3) * KT * 64 + lane;
    const short8* w0l = Wlo + (size_t)(nb + 0) * KT * 64 + lane;
    const short8* w1l = Wlo + (size_t)(nb + 1) * KT * 64 + lane;
    const short8* w2l = Wlo + (size_t)(nb + 2) * KT * 64 + lane;
    const short8* w3l = Wlo + (size_t)(nb + 3) * KT * 64 + lane;
    f32x4 acc0[4] = {}, acc1[4] = {};

    for (int kt = 0; kt < KT; kt++) {
        size_t o = (size_t)kt * 64;
        short8 A0H = a0h[o], A1H = a1h[o], A0L = a0l[o], A1L = a1l[o];
        short8 WH0 = w0h[o], WL0 = w0l[o];
        MFMA(acc0[0], A0H, WH0); MFMA(acc1[0], A1H, WH0);
        MFMA(acc0[0], A0H, WL0); MFMA(acc1[0], A1H, WL0);
        MFMA(acc0[0], A0L, WH0); MFMA(acc1[0], A1L, WH0);
        short8 WH1 = w1h[o], WL1 = w1l[o];
        MFMA(acc0[1], A0H, WH1); MFMA(acc1[1], A1H, WH1);
        MFMA(acc0[1], A0H, WL1); MFMA(acc1[1], A1H, WL1);
        MFMA(acc0[1], A0L, WH1); MFMA(acc1[1], A1L, WH1);
        short8 WH2 = w2h[o], WL2 = w2l[o];
        MFMA(acc0[2], A0H, WH2); MFMA(acc1[2], A1H, WH2);
        MFMA(acc0[2], A0H, WL2); MFMA(acc1[2], A1H, WL2);
        MFMA(acc0[2], A0L, WH2); MFMA(acc1[2], A1L, WH2);
        short8 WH3 = w3h[o], WL3 = w3l[o];
        MFMA(acc0[3], A0H, WH3); MFMA(acc1[3], A1H, WH3);
        MFMA(acc0[3], A0H, WL3); MFMA(acc1[3], A1H, WL3);
        MFMA(acc0[3], A0L, WH3); MFMA(acc1[3], A1L, WH3);
    }
    int rsub = (lane >> 4) * 4, cn = lane & 15;
    int row0 = (m16 + 0) * 16 + rsub;
    int row1 = (m16 + 1) * 16 + rsub;
#pragma unroll
    for (int j = 0; j < 4; j++) {
        int col = (nb + j) * 16 + cn;
        float bb = bias ? bias[col] : 0.f;
#pragma unroll
        for (int r = 0; r < 4; r++) {
            C[(size_t)(row0 + r) * N + col] = acc0[j][r] + bb;
            C[(size_t)(row1 + r) * N + col] = acc1[j][r] + bb;
        }
    }
}

// ---------------------------------------------------------------------------
// BM=32 GEMM for the pre-loop tmp2. Grid (M/32, N/64).
// ---------------------------------------------------------------------------
__global__ __launch_bounds__(256) void gemm_bm32(
    const short8* __restrict__ Ahi, const short8* __restrict__ Alo,
    const short8* __restrict__ Whi, const short8* __restrict__ Wlo,
    const float* __restrict__ bias, float* __restrict__ C,
    int KT, int N) {
    int tid = threadIdx.x, lane = tid & 63, wave = tid >> 6;
    int m16 = blockIdx.x * 2 + (wave & 1);
    int n16 = blockIdx.y * 4 + (wave >> 1) * 2;
    const short8* ah = Ahi + (size_t)m16 * KT * 64 + lane;
    const short8* al = Alo + (size_t)m16 * KT * 64 + lane;
    const short8* w0h = Whi + (size_t)n16 * KT * 64 + lane;
    const short8* w1h = w0h + (size_t)KT * 64;
    const short8* w0l = Wlo + (size_t)n16 * KT * 64 + lane;
    const short8* w1l = w0l + (size_t)KT * 64;
    f32x4 a0 = {0,0,0,0}, a1 = {0,0,0,0};
    for (int kt = 0; kt < KT; kt++) {
        size_t o = (size_t)kt * 64;
        short8 AH = ah[o], AL = al[o];
        short8 W0H = w0h[o], W0L = w0l[o], W1H = w1h[o], W1L = w1l[o];
        MFMA(a0, AH, W0H); MFMA(a1, AH, W1H);
        MFMA(a0, AH, W0L); MFMA(a1, AH, W1L);
        MFMA(a0, AL, W0H); MFMA(a1, AL, W1H);
    }
    int rsub = (lane >> 4) * 4, cn = lane & 15;
    float b0 = bias ? bias[(n16 + 0) * 16 + cn] : 0.f;
    float b1 = bias ? bias[(n16 + 1) * 16 + cn] : 0.f;
#pragma unroll
    for (int r = 0; r < 4; r++) {
        int row = m16 * 16 + rsub + r;
        C[(size_t)row * N + (n16 + 0) * 16 + cn] = a0[r] + b0;
        C[(size_t)row * N + (n16 + 1) * 16 + cn] = a1[r] + b1;
    }
}

// ---------------------------------------------------------------------------
// Encoder GRU step: 12 waves = (gate x K-quarter); each wave covers FOUR m16
// tiles -> 12 MFMA per kt on 10 loads (2 W amortized over 4 tiles), 4
// independent acc chains per wave. Grid (64, 4), 12 waves/CU unchanged.
// Numeric change vs R6: gate sum is 4 K-quarter partials (fp-reorder only).
// ---------------------------------------------------------------------------
__global__ __launch_bounds__(768) void enc_gru3(
    const short8* __restrict__ hinH8, const short8* __restrict__ hinL8,
    const short8* __restrict__ WrH, const short8* __restrict__ WrL,
    const short8* __restrict__ WzH, const short8* __restrict__ WzL,
    const short8* __restrict__ WnH, const short8* __restrict__ WnL,
    const float* __restrict__ gi,
    const float* __restrict__ bih, const float* __restrict__ bhh,
    const float* __restrict__ hinF, float* __restrict__ houtF,
    short* __restrict__ hoH, short* __restrict__ hoL,
    short* __restrict__ eaHi, short* __restrict__ eaLo,
    const int* __restrict__ x_len, int t) {
    __shared__ float sC[12][4][16][16];
    __shared__ float sHo[4][16][16];
    __shared__ float sEo[4][16][16];
    int tid = threadIdx.x, lane = tid & 63, wave = tid >> 6;  // wave 0..11
    int g = blockIdx.x;
    int m16a = blockIdx.y * 4;
    int gate = wave >> 2, q = wave & 3;   // K-quarter: kt in [q*8, q*8+8)
    const short8* WH0 = (gate == 0) ? WrH : (gate == 1) ? WzH : WnH;
    const short8* WL0 = (gate == 0) ? WrL : (gate == 1) ? WzL : WnL;
    const short8* wh = WH0 + (size_t)g * 32 * 64 + (size_t)q * 8 * 64 + lane;
    const short8* wl = WL0 + (size_t)g * 32 * 64 + (size_t)q * 8 * 64 + lane;
    const short8* a0h = hinH8 + (size_t)(m16a + 0) * 32 * 64 + (size_t)q * 8 * 64 + lane;
    const short8* a0l = hinL8 + (size_t)(m16a + 0) * 32 * 64 + (size_t)q * 8 * 64 + lane;
    const short8* a1h = a0h + (size_t)32 * 64;
    const short8* a1l = a0l + (size_t)32 * 64;
    const short8* a2h = a1h + (size_t)32 * 64;
    const short8* a2l = a1l + (size_t)32 * 64;
    const short8* a3h = a2h + (size_t)32 * 64;
    const short8* a3l = a2l + (size_t)32 * 64;
    f32x4 acc0 = {0,0,0,0}, acc1 = {0,0,0,0}, acc2 = {0,0,0,0}, acc3 = {0,0,0,0};
    for (int kt = 0; kt < 8; kt++) {
        size_t o = (size_t)kt * 64;
        short8 WH = wh[o], WL = wl[o];
        short8 A0H = a0h[o], A0L = a0l[o];
        MFMA(acc0, A0H, WH); MFMA(acc0, A0H, WL); MFMA(acc0, A0L, WH);
        short8 A1H = a1h[o], A1L = a1l[o];
        MFMA(acc1, A1H, WH); MFMA(acc1, A1H, WL); MFMA(acc1, A1L, WH);
        short8 A2H = a2h[o], A2L = a2l[o];
        MFMA(acc2, A2H, WH); MFMA(acc2, A2H, WL); MFMA(acc2, A2L, WH);
        short8 A3H = a3h[o], A3L = a3l[o];
        MFMA(acc3, A3H, WH); MFMA(acc3, A3H, WL); MFMA(acc3, A3L, WH);
    }
    {
        int slot = (gate << 2) + q;
        int rsub = (lane >> 4) << 2, cn = lane & 15;
#pragma unroll
        for (int j = 0; j < 4; j++) {
            sC[slot][0][rsub + j][cn] = acc0[j];
            sC[slot][1][rsub + j][cn] = acc1[j];
            sC[slot][2][rsub + j][cn] = acc2[j];
            sC[slot][3][rsub + j][cn] = acc3[j];
        }
    }
    __syncthreads();
    if (wave < 4) {
        int tile = wave;
        int m16 = m16a + tile;
        int cu = g * 16 + (lane & 15);
        int rsub = (lane >> 4) << 2;
        float b_r = bih[cu] + bhh[cu];
        float b_z = bih[UDIM + cu] + bhh[UDIM + cu];
        float b_nh = bhh[2 * UDIM + cu];
        float b_ni = bih[2 * UDIM + cu];
        int growLocal = (t & 7) * 256;
#pragma unroll
        for (int j = 0; j < 4; j++) {
            int rr = rsub + j, cc = lane & 15;
            int b = m16 * 16 + rr;
            const float* gr = gi + (size_t)(growLocal + b) * U3;
            float rS = sC[0][tile][rr][cc] + sC[1][tile][rr][cc] +
                       sC[2][tile][rr][cc] + sC[3][tile][rr][cc];
            float zS = sC[4][tile][rr][cc] + sC[5][tile][rr][cc] +
                       sC[6][tile][rr][cc] + sC[7][tile][rr][cc];
            float nS = sC[8][tile][rr][cc] + sC[9][tile][rr][cc] +
                       sC[10][tile][rr][cc] + sC[11][tile][rr][cc];
            float rg = sigm(rS + gr[cu] + b_r);
            float zg = sigm(zS + gr[UDIM + cu] + b_z);
            float nn = tanhf(gr[2 * UDIM + cu] + b_ni + rg * (nS + b_nh));
            float hp = hinF[(size_t)b * UDIM + cu];
            float hv = (1.f - zg) * nn + zg * hp;
            bool msk = t < x_len[b];
            float ho = msk ? hv : hp;
            houtF[(size_t)b * UDIM + cu] = ho;
            sHo[tile][rr][cc] = ho;
            sEo[tile][rr][cc] = msk ? hv : 0.f;
        }
    }
    __syncthreads();
    if (wave >= 4 && wave < 8 && lane < 32) {
        int tile = wave - 4;
        int m16 = m16a + tile;
        int rr = lane >> 1, oct = lane & 1;
        int brow = m16 * 16 + rr;
        int u0 = g * 16 + oct * 8;
        float v[8];
#pragma unroll
        for (int j = 0; j < 8; j++) v[j] = sHo[tile][rr][oct * 8 + j];
        writeSplit8(hoH, hoL, pkChunk(brow, u0, UDIM), v);
#pragma unroll
        for (int j = 0; j < 8; j++) v[j] = sEo[tile][rr][oct * 8 + j];
        writeSplit8(eaHi, eaLo, pkChunk(brow * SLEN + t, u0, UDIM), v);
    }
}

// ---------------------------------------------------------------------------
// Decoder GRU step: 12 waves = (gate x K-quarter); each wave covers FOUR m16
// tiles. h-part quarter = 8 kt, gx-part quarter = 12 kt. Grid (64, 4).
// ---------------------------------------------------------------------------
__global__ __launch_bounds__(768) void dec_gru3(
    const short8* __restrict__ hinH8, const short8* __restrict__ hinL8,
    const short8* __restrict__ gxH8, const short8* __restrict__ gxL8,
    const short8* __restrict__ WrH, const short8* __restrict__ WrL,
    const short8* __restrict__ WzH, const short8* __restrict__ WzL,
    const short8* __restrict__ WnhH, const short8* __restrict__ WnhL,
    const short8* __restrict__ WniH, const short8* __restrict__ WniL,
    const float* __restrict__ bih, const float* __restrict__ bhh,
    const float* __restrict__ hinF, float* __restrict__ houtF,
    short* __restrict__ hoH, short* __restrict__ hoL) {
    __shared__ float sC[16][4][16][16];   // r:0-3 z:4-7 nh:8-11 ni:12-15
    __shared__ float sHo[4][16][16];
    int tid = threadIdx.x, lane = tid & 63, wave = tid >> 6;  // 0..11
    int g = blockIdx.x;
    int m16a = blockIdx.y * 4;
    int gate = wave >> 2, q = wave & 3;
    const short8* a0h = hinH8 + (size_t)(m16a + 0) * 32 * 64 + (size_t)q * 8 * 64 + lane;
    const short8* a0l = hinL8 + (size_t)(m16a + 0) * 32 * 64 + (size_t)q * 8 * 64 + lane;
    const short8* a1h = a0h + (size_t)32 * 64;
    const short8* a1l = a0l + (size_t)32 * 64;
    const short8* a2h = a1h + (size_t)32 * 64;
    const short8* a2l = a1l + (size_t)32 * 64;
    const short8* a3h = a2h + (size_t)32 * 64;
    const short8* a3l = a2l + (size_t)32 * 64;
    const short8* g0h = gxH8 + (size_t)(m16a + 0) * 48 * 64 + (size_t)q * 12 * 64 + lane;
    const short8* g0l = gxL8 + (size_t)(m16a + 0) * 48 * 64 + (size_t)q * 12 * 64 + lane;
    const short8* g1h = g0h + (size_t)48 * 64;
    const short8* g1l = g0l + (size_t)48 * 64;
    const short8* g2h = g1h + (size_t)48 * 64;
    const short8* g2l = g1l + (size_t)48 * 64;
    const short8* g3h = g2h + (size_t)48 * 64;
    const short8* g3l = g2l + (size_t)48 * 64;
    const short8 *whA, *wlA, *whB, *wlB;
    if (gate == 0) {
        whA = WrH + (size_t)g * 80 * 64 + (size_t)q * 8 * 64 + lane;
        wlA = WrL + (size_t)g * 80 * 64 + (size_t)q * 8 * 64 + lane;
        whB = WrH + (size_t)g * 80 * 64 + (size_t)(32 + q * 12) * 64 + lane;
        wlB = WrL + (size_t)g * 80 * 64 + (size_t)(32 + q * 12) * 64 + lane;
    } else if (gate == 1) {
        whA = WzH + (size_t)g * 80 * 64 + (size_t)q * 8 * 64 + lane;
        wlA = WzL + (size_t)g * 80 * 64 + (size_t)q * 8 * 64 + lane;
        whB = WzH + (size_t)g * 80 * 64 + (size_t)(32 + q * 12) * 64 + lane;
        wlB = WzL + (size_t)g * 80 * 64 + (size_t)(32 + q * 12) * 64 + lane;
    } else {
        whA = WnhH + (size_t)g * 32 * 64 + (size_t)q * 8 * 64 + lane;
        wlA = WnhL + (size_t)g * 32 * 64 + (size_t)q * 8 * 64 + lane;
        whB = WniH + (size_t)g * 48 * 64 + (size_t)q * 12 * 64 + lane;
        wlB = WniL + (size_t)g * 48 * 64 + (size_t)q * 12 * 64 + lane;
    }
    f32x4 accA0 = {0,0,0,0}, accA1 = {0,0,0,0}, accA2 = {0,0,0,0}, accA3 = {0,0,0,0};
    f32x4 accB0 = {0,0,0,0}, accB1 = {0,0,0,0}, accB2 = {0,0,0,0}, accB3 = {0,0,0,0};
    for (int kt = 0; kt < 8; kt++) {
        size_t o = (size_t)kt * 64;
        short8 WH = whA[o], WL = wlA[o];
        short8 A0H = a0h[o], A0L = a0l[o];
        MFMA(accA0, A0H, WH); MFMA(accA0, A0H, WL); MFMA(accA0, A0L, WH);
        short8 A1H = a1h[o], A1L = a1l[o];
        MFMA(accA1, A1H, WH); MFMA(accA1, A1H, WL); MFMA(accA1, A1L, WH);
        short8 A2H = a2h[o], A2L = a2l[o];
        MFMA(accA2, A2H, WH); MFMA(accA2, A2H, WL); MFMA(accA2, A2L, WH);
        short8 A3H = a3h[o], A3L = a3l[o];
        MFMA(accA3, A3H, WH); MFMA(accA3, A3H, WL); MFMA(accA3, A3L, WH);
    }
    for (int kt = 0; kt < 12; kt++) {
        size_t o = (size_t)kt * 64;
        short8 WH = whB[o], WL = wlB[o];
        short8 G0H = g0h[o], G0L = g0l[o];
        MFMA(accB0, G0H, WH); MFMA(accB0, G0H, WL); MFMA(accB0, G0L, WH);
        short8 G1H = g1h[o], G1L = g1l[o];
        MFMA(accB1, G1H, WH); MFMA(accB1, G1H, WL); MFMA(accB1, G1L, WH);
        short8 G2H = g2h[o], G2L = g2l[o];
        MFMA(accB2, G2H, WH); MFMA(accB2, G2H, WL); MFMA(accB2, G2L, WH);
        short8 G3H = g3h[o], G3L = g3l[o];
        MFMA(accB3, G3H, WH); MFMA(accB3, G3H, WL); MFMA(accB3, G3L, WH);
    }
    {
        int rsub = (lane >> 4) << 2, cn = lane & 15;
        if (gate < 2) {
            int slot = (gate << 2) + q;
#pragma unroll
            for (int j = 0; j < 4; j++) {
                sC[slot][0][rsub + j][cn] = accA0[j] + accB0[j];
                sC[slot][1][rsub + j][cn] = accA1[j] + accB1[j];
                sC[slot][2][rsub + j][cn] = accA2[j] + accB2[j];
                sC[slot][3][rsub + j][cn] = accA3[j] + accB3[j];
            }
        } else {
#pragma unroll
            for (int j = 0; j < 4; j++) {
                sC[8 + q][0][rsub + j][cn] = accA0[j];   // nh partials
                sC[8 + q][1][rsub + j][cn] = accA1[j];
                sC[8 + q][2][rsub + j][cn] = accA2[j];
                sC[8 + q][3][rsub + j][cn] = accA3[j];
                sC[12 + q][0][rsub + j][cn] = accB0[j];  // ni partials
                sC[12 + q][1][rsub + j][cn] = accB1[j];
                sC[12 + q][2][rsub + j][cn] = accB2[j];
                sC[12 + q][3][rsub + j][cn] = accB3[j];
            }
        }
    }
    __syncthreads();
    if (wave < 4) {
        int tile = wave;
        int m16 = m16a + tile;
        int cu = g * 16 + (lane & 15);
        int rsub = (lane >> 4) << 2;
        float b_r = bih[cu] + bhh[cu];
        float b_z = bih[UDIM + cu] + bhh[UDIM + cu];
        float b_nh = bhh[2 * UDIM + cu];
        float b_ni = bih[2 * UDIM + cu];
#pragma unroll
        for (int j = 0; j < 4; j++) {
            int rr = rsub + j, cc = lane & 15;
            int b = m16 * 16 + rr;
            float rS = sC[0][tile][rr][cc] + sC[1][tile][rr][cc] +
                       sC[2][tile][rr][cc] + sC[3][tile][rr][cc];
            float zS = sC[4][tile][rr][cc] + sC[5][tile][rr][cc] +
                       sC[6][tile][rr][cc] + sC[7][tile][rr][cc];
            float nhS = sC[8][tile][rr][cc] + sC[9][tile][rr][cc] +
                        sC[10][tile][rr][cc] + sC[11][tile][rr][cc];
            float niS = sC[12][tile][rr][cc] + sC[13][tile][rr][cc] +
                        sC[14][tile][rr][cc] + sC[15][tile][rr][cc];
            float rg = sigm(rS + b_r);
            float zg = sigm(zS + b_z);
            float nn = tanhf(niS + b_ni + rg * (nhS + b_nh));
            float hp = hinF[(size_t)b * UDIM + cu];
            float hv = (1.f - zg) * nn + zg * hp;
            houtF[(size_t)b * UDIM + cu] = hv;
            sHo[tile][rr][cc] = hv;
        }
    }
    __syncthreads();
    if (wave >= 4 && wave < 8 && lane < 32) {
        int tile = wave - 4;
        int m16 = m16a + tile;
        int rr = lane >> 1, oct = lane & 1;
        int brow = m16 * 16 + rr;
        int u0 = g * 16 + oct * 8;
        float v[8];
#pragma unroll
        for (int j = 0; j < 8; j++) v[j] = sHo[tile][rr][oct * 8 + j];
        writeSplit8(hoH, hoL, pkChunk(brow, u0, UDIM), v);
    }
}

// ---------------------------------------------------------------------------
// Attention + ctx + emb -> gx split-pack. 1024-thread blocks (16 waves/CU):
// score pass 16-wave s-stride; ctx pass 8-way s-split with LDS combine;
// emb reads pre-transposed bias-folded o2hT row (coalesced).
// ---------------------------------------------------------------------------
__global__ __launch_bounds__(1024) void attn_ctx(
    const float* __restrict__ encProj,
    const short* __restrict__ eaHi, const short* __restrict__ eaLo,
    const float* __restrict__ tmp2, const float* __restrict__ V_W,
    const float* __restrict__ V_b,
    const float* __restrict__ o2hT,
    const int* __restrict__ idx, short* __restrict__ gxHi, short* __restrict__ gxLo) {
    int b = blockIdx.x;
    int tid = threadIdx.x, lane = tid & 63, wave = tid >> 6;
    __shared__ float s_t2[UDIM];
    __shared__ float s_v[UDIM];
    __shared__ float s_attn[SLEN];
    __shared__ float s_part[7][128][9];  // pad 9 floats: conflict-free combine
    for (int u = tid; u < UDIM; u += 1024) {
        s_t2[u] = tmp2[(size_t)b * UDIM + u];
        s_v[u] = V_W[u];
    }
    __syncthreads();
    for (int s = wave; s < SLEN; s += 16) {
        const float4* ep4 = (const float4*)(encProj + ((size_t)b * SLEN + s) * UDIM);
        float p = 0.f;
        for (int u4 = lane; u4 < UDIM / 4; u4 += 64) {
            float4 e = ep4[u4];
            int u = 4 * u4;
            p += tanhf_fast(e.x + s_t2[u]) * s_v[u] +
                 tanhf_fast(e.y + s_t2[u + 1]) * s_v[u + 1] +
                 tanhf_fast(e.z + s_t2[u + 2]) * s_v[u + 2] +
                 tanhf_fast(e.w + s_t2[u + 3]) * s_v[u + 3];
        }
#pragma unroll
        for (int off = 32; off > 0; off >>= 1) p += __shfl_xor(p, off);
        if (lane == 0) s_attn[s] = p + V_b[0];
    }
    __syncthreads();
    if (tid < 64) {
        float v = s_attn[tid];
        float mx = v;
#pragma unroll
        for (int off = 32; off > 0; off >>= 1) mx = fmaxf(mx, __shfl_xor(mx, off));
        float e = expf(v - mx);
        float sum = e;
#pragma unroll
        for (int off = 32; off > 0; off >>= 1) sum += __shfl_xor(sum, off);
        s_attn[tid] = e / sum;
    }
    __syncthreads();
    {
        int grp = tid >> 7, tu = tid & 127;  // 8 s-groups x 128 u-threads
        int u0 = tu * 8;
        float a[8] = {0, 0, 0, 0, 0, 0, 0, 0};
        const short8* hi8 = (const short8*)eaHi;
        const short8* lo8 = (const short8*)eaLo;
        int lanePart = 16 * ((u0 >> 3) & 3);
        int colPart = u0 >> 5;
        for (int s = grp * 8; s < grp * 8 + 8; s++) {
            int r = b * SLEN + s;
            size_t ch = ((size_t)(r >> 4) * (UDIM >> 5) + colPart) * 64 + (r & 15) + lanePart;
            S8 h, l;
            h.v = hi8[ch];
            l.v = lo8[ch];
            float w = s_attn[s];
#pragma unroll
            for (int j = 0; j < 8; j++) a[j] += w * (bf2f(h.s[j]) + bf2f(l.s[j]));
        }
        if (grp) {
#pragma unroll
            for (int j = 0; j < 8; j++) s_part[grp - 1][tu][j] = a[j];
        }
        __syncthreads();
        if (tid < 128) {
#pragma unroll
            for (int gg = 0; gg < 7; gg++)
#pragma unroll
                for (int j = 0; j < 8; j++) a[j] += s_part[gg][tu][j];
            writeSplit8(gxHi, gxLo, pkChunk(b, u0, GXW), a);
        } else if (tid < 192) {
            int e0 = (tid - 128) * 8;
            int ib = idx[b];
            const float* row = o2hT + (size_t)ib * EDIM + e0;
            float v[8];
#pragma unroll
            for (int j = 0; j < 8; j++) v[j] = row[j];
            writeSplit8(gxHi, gxLo, pkChunk(b, UDIM + e0, GXW), v);
        }
    }
}

// ---------------------------------------------------------------------------
// Merged: pred=h@fc^T+b + parallel first-max argmax (blocks 0..15) AND
// tmp2=h@W2^T+b for the next step (blocks 16..143).
// ---------------------------------------------------------------------------
__global__ __launch_bounds__(256) void fcw2(
    const short8* __restrict__ hHi, const short8* __restrict__ hLo,
    const short8* __restrict__ fcH, const short8* __restrict__ fcL,
    const float* __restrict__ fc_b, float* __restrict__ pred,
    int* __restrict__ idx,
    const short8* __restrict__ w2H, const short8* __restrict__ w2L,
    const float* __restrict__ W2_b, float* __restrict__ tmp2) {
    __shared__ float sP[16][129];
    int tid = threadIdx.x, lane = tid & 63, wave = tid >> 6;
    if (blockIdx.x < 16) {
        int fm = blockIdx.x;
        const short8* ah = hHi + (size_t)fm * 32 * 64 + lane;
        const short8* al = hLo + (size_t)fm * 32 * 64 + lane;
        int n0 = 2 * wave, n1 = 2 * wave + 1;
        const short8* w0h = fcH + (size_t)n0 * 32 * 64 + lane;
        const short8* w0l = fcL + (size_t)n0 * 32 * 64 + lane;
        const short8* w1h = fcH + (size_t)n1 * 32 * 64 + lane;
        const short8* w1l = fcL + (size_t)n1 * 32 * 64 + lane;
        f32x4 a0 = {0,0,0,0}, a1 = {0,0,0,0};
        for (int kt = 0; kt < 32; kt++) {
            size_t o = (size_t)kt * 64;
            short8 AH = ah[o], AL = al[o];
            short8 W0H = w0h[o], W0L = w0l[o], W1H = w1h[o], W1L = w1l[o];
            MFMA(a0, AH, W0H); MFMA(a1, AH, W1H);
            MFMA(a0, AH, W0L); MFMA(a1, AH, W1L);
            MFMA(a0, AL, W0H); MFMA(a1, AL, W1H);
        }
        int cn = lane & 15, rsub = (lane >> 4) << 2;
#pragma unroll
        for (int j = 0; j < 4; j++) {
            sP[rsub + j][n0 * 16 + cn] = a0[j] + fc_b[n0 * 16 + cn];
            sP[rsub + j][n1 * 16 + cn] = a1[j] + fc_b[n1 * 16 + cn];
        }
        __syncthreads();
        {
            int row = tid >> 4, c0 = (tid & 15) * 8;
            float* pr = pred + (size_t)(fm * 16 + row) * VOUTD;
#pragma unroll
            for (int j = 0; j < 8; j++) pr[c0 + j] = sP[row][c0 + j];
        }
        if (tid < 128) {
            // 8 lanes per row, first-max semantics (strict > in scan order,
            // smaller index wins ties across segments)
            int row = tid >> 3, seg = tid & 7;
            float v = -1e30f;
            int bi = 0;
            int c0 = seg * 16;
            for (int j = c0; j < c0 + 16; j++) {
                float w = sP[row][j];
                if (w > v) { v = w; bi = j; }
            }
#pragma unroll
            for (int off = 1; off < 8; off <<= 1) {
                float ov = __shfl_xor(v, off);
                int obi = __shfl_xor(bi, off);
                if (ov > v || (ov == v && obi < bi)) { v = ov; bi = obi; }
            }
            if (seg == 0) idx[fm * 16 + row] = bi;
        }
    } else {
        int lin = blockIdx.x - 16;       // 0..127
        int bx = lin & 7, by = lin >> 3; // bm32 grid (8, 16)
        int m16 = bx * 2 + (wave & 1);
        int n16 = by * 4 + (wave >> 1) * 2;
        const short8* ah = hHi + (size_t)m16 * 32 * 64 + lane;
        const short8* al = hLo + (size_t)m16 * 32 * 64 + lane;
        const short8* w0h = w2H + (size_t)n16 * 32 * 64 + lane;
        const short8* w1h = w0h + (size_t)32 * 64;
        const short8* w0l = w2L + (size_t)n16 * 32 * 64 + lane;
        const short8* w1l = w0l + (size_t)32 * 64;
        f32x4 a0 = {0,0,0,0}, a1 = {0,0,0,0};
        for (int kt = 0; kt < 32; kt++) {
            size_t o = (size_t)kt * 64;
            short8 AH = ah[o], AL = al[o];
            short8 W0H = w0h[o], W0L = w0l[o], W1H = w1h[o], W1L = w1l[o];
            MFMA(a0, AH, W0H); MFMA(a1, AH, W1H);
            MFMA(a0, AH, W0L); MFMA(a1, AH, W1L);
            MFMA(a0, AL, W0H); MFMA(a1, AL, W1H);
        }
        int rsub = (lane >> 4) * 4, cn = lane & 15;
        float b0 = W2_b[(n16 + 0) * 16 + cn];
        float b1 = W2_b[(n16 + 1) * 16 + cn];
#pragma unroll
        for (int r = 0; r < 4; r++) {
            int row = m16 * 16 + rsub + r;
            tmp2[(size_t)row * UDIM + (n16 + 0) * 16 + cn] = a0[r] + b0;
            tmp2[(size_t)row * UDIM + (n16 + 1) * 16 + cn] = a1[r] + b1;
        }
    }
}

// ---------------------------------------------------------------------------
extern "C" void kernel_launch(void* const* d_in, const int* in_sizes, int n_in,
                              void* d_out, int out_size, void* d_ws, size_t ws_size,
                              hipStream_t stream) {
    const float* x       = (const float*)d_in[0];
    const int*   x_len   = (const int*)d_in[1];
    const float* enc_Wih = (const float*)d_in[2];
    const float* enc_Whh = (const float*)d_in[3];
    const float* enc_bih = (const float*)d_in[4];
    const float* enc_bhh = (const float*)d_in[5];
    const float* dec_Wih = (const float*)d_in[6];
    const float* dec_Whh = (const float*)d_in[7];
    const float* dec_bih = (const float*)d_in[8];
    const float* dec_bhh = (const float*)d_in[9];
    const float* o2h_W   = (const float*)d_in[10];
    const float* o2h_b   = (const float*)d_in[11];
    const float* fc_W    = (const float*)d_in[12];
    const float* fc_b    = (const float*)d_in[13];
    const float* W1_W    = (const float*)d_in[14];
    const float* W1_b    = (const float*)d_in[15];
    const float* W2_W    = (const float*)d_in[16];
    const float* W2_b    = (const float*)d_in[17];
    const float* V_W     = (const float*)d_in[18];
    const float* V_b     = (const float*)d_in[19];
    float* out = (float*)d_out;

    char* p = (char*)d_ws;
    auto alloc = [&](size_t bytes) -> char* {
        char* q = p;
        p += (bytes + 255) & ~(size_t)255;
        return q;
    };
    float* hAF  = (float*)alloc((size_t)BATCH * UDIM * 4);
    float* hBF  = (float*)alloc((size_t)BATCH * UDIM * 4);
    short* hAH  = (short*)alloc((size_t)BATCH * UDIM * 2);
    short* hAL  = (short*)alloc((size_t)BATCH * UDIM * 2);
    short* hBH  = (short*)alloc((size_t)BATCH * UDIM * 2);
    short* hBL  = (short*)alloc((size_t)BATCH * UDIM * 2);
    float* tmp2 = (float*)alloc((size_t)BATCH * UDIM * 4);
    short* gxHi = (short*)alloc((size_t)BATCH * GXW * 2);
    short* gxLo = (short*)alloc((size_t)BATCH * GXW * 2);
    short* encAHi = (short*)alloc((size_t)BATCH * SLEN * UDIM * 2);
    short* encALo = (short*)alloc((size_t)BATCH * SLEN * UDIM * 2);
    float* encProjF = (float*)alloc((size_t)BATCH * SLEN * UDIM * 4);
    float* gihBuf = (float*)alloc((size_t)8 * BATCH * U3 * 4);
    short* eWihH = (short*)alloc((size_t)U3 * VIND * 2);
    short* eWihL = (short*)alloc((size_t)U3 * VIND * 2);
    short* eWrH = (short*)alloc((size_t)UDIM * UDIM * 2);
    short* eWrL = (short*)alloc((size_t)UDIM * UDIM * 2);
    short* eWzH = (short*)alloc((size_t)UDIM * UDIM * 2);
    short* eWzL = (short*)alloc((size_t)UDIM * UDIM * 2);
    short* eWnH = (short*)alloc((size_t)UDIM * UDIM * 2);
    short* eWnL = (short*)alloc((size_t)UDIM * UDIM * 2);
    short* dWrH = (short*)alloc((size_t)UDIM * 2560 * 2);
    short* dWrL = (short*)alloc((size_t)UDIM * 2560 * 2);
    short* dWzH = (short*)alloc((size_t)UDIM * 2560 * 2);
    short* dWzL = (short*)alloc((size_t)UDIM * 2560 * 2);
    short* dWnhH = (short*)alloc((size_t)UDIM * UDIM * 2);
    short* dWnhL = (short*)alloc((size_t)UDIM * UDIM * 2);
    short* dWniH = (short*)alloc((size_t)UDIM * GXW * 2);
    short* dWniL = (short*)alloc((size_t)UDIM * GXW * 2);
    short* w1Hi = (short*)alloc((size_t)UDIM * UDIM * 2);
    short* w1Lo = (short*)alloc((size_t)UDIM * UDIM * 2);
    short* w2Hi = (short*)alloc((size_t)UDIM * UDIM * 2);
    short* w2Lo = (short*)alloc((size_t)UDIM * UDIM * 2);
    short* fcHi = (short*)alloc((size_t)VOUTD * UDIM * 2);
    short* fcLo = (short*)alloc((size_t)VOUTD * UDIM * 2);
    short* xHi  = (short*)alloc((size_t)SLEN * BATCH * VIND * 2);
    short* xLo  = (short*)alloc((size_t)SLEN * BATCH * VIND * 2);
    int*   idx  = (int*)alloc(BATCH * 4);
    float* o2hT = (float*)alloc((size_t)VOUTD * EDIM * 4);

    init_kernel<<<(BATCH * UDIM + 255) / 256, 256, 0, stream>>>(
        hAF, hAH, hAL, out, idx, o2h_W, o2h_b, o2hT);

    // ---- single packing kernel for all weights + x ----
    {
        PackArgs pa;
        int cs = 0, n = 0;
        auto seg = [&](const float* sA, int KA, int offA, const float* sB, int KB,
                       int offB, short* Hi, short* Lo, int R) {
            pa.s[n] = {sA, sB, Hi, Lo, KA, KB, offA, offB, cs};
            cs += R * (KA + KB) / 8;
            n++;
        };
        seg(enc_Wih, VIND, 0, nullptr, 0, 0, eWihH, eWihL, U3);
        seg(enc_Whh, UDIM, 0, nullptr, 0, 0, eWrH, eWrL, UDIM);
        seg(enc_Whh, UDIM, UDIM, nullptr, 0, 0, eWzH, eWzL, UDIM);
        seg(enc_Whh, UDIM, 2 * UDIM, nullptr, 0, 0, eWnH, eWnL, UDIM);
        seg(dec_Whh, UDIM, 0, dec_Wih, GXW, 0, dWrH, dWrL, UDIM);
        seg(dec_Whh, UDIM, UDIM, dec_Wih, GXW, UDIM, dWzH, dWzL, UDIM);
        seg(dec_Whh, UDIM, 2 * UDIM, nullptr, 0, 0, dWnhH, dWnhL, UDIM);
        seg(dec_Wih, GXW, 2 * UDIM, nullptr, 0, 0, dWniH, dWniL, UDIM);
        seg(W1_W, UDIM, 0, nullptr, 0, 0, w1Hi, w1Lo, UDIM);
        seg(W2_W, UDIM, 0, nullptr, 0, 0, w2Hi, w2Lo, UDIM);
        seg(fc_W, UDIM, 0, nullptr, 0, 0, fcHi, fcLo, VOUTD);
        seg(x, VIND, 0, nullptr, 0, 0, xHi, xLo, SLEN * BATCH);
        pack_all<<<(cs + 255) / 256, 256, 0, stream>>>(pa, cs);
    }

    // ---- encoder: 8 chunks of (gi chunk-GEMM + 8 fused GRU steps) ----
    float* hcF = hAF; float* hnF = hBF;
    short *hcH = hAH, *hcL = hAL, *hnH = hBH, *hnL = hBL;
    for (int c = 0; c < 8; c++) {
        gemm_w<<<dim3(32, 24), 256, 0, stream>>>(
            (const short8*)xHi + (size_t)c * 128 * 4 * 64,
            (const short8*)xLo + (size_t)c * 128 * 4 * 64,
            (const short8*)eWihH, (const short8*)eWihL,
            nullptr, gihBuf, VIND / 32, U3);
        for (int tt = 0; tt < 8; tt++) {
            int t = c * 8 + tt;
            enc_gru3<<<dim3(64, 4), 768, 0, stream>>>(
                (const short8*)hcH, (const short8*)hcL,
                (const short8*)eWrH, (const short8*)eWrL,
                (const short8*)eWzH, (const short8*)eWzL,
                (const short8*)eWnH, (const short8*)eWnL,
                gihBuf, enc_bih, enc_bhh, hcF, hnF, hnH, hnL,
                encAHi, encALo, x_len, t);
            { float* tf = hcF; hcF = hnF; hnF = tf; }
            { short* th = hcH; hcH = hnH; hnH = th; th = hcL; hcL = hnL; hnL = th; }
        }
    }

    // ---- enc_proj = enc_out @ W1^T + W1_b (fp32, BN=128 blocks) ----
    gemm_w<<<dim3(SLEN * BATCH / 64, UDIM / 128), 256, 0, stream>>>(
        (const short8*)encAHi, (const short8*)encALo,
        (const short8*)w1Hi, (const short8*)w1Lo,
        W1_b, encProjF, UDIM / 32, UDIM);

    // ---- initial tmp2 from encoder hidden ----
    gemm_bm32<<<dim3(BATCH / 32, UDIM / 64), 256, 0, stream>>>(
        (const short8*)hcH, (const short8*)hcL,
        (const short8*)w2Hi, (const short8*)w2Lo,
        W2_b, tmp2, UDIM / 32, UDIM);

    // ---- greedy decode: 24 steps x 3 dispatches ----
    for (int st = 0; st < TDEC - 1; st++) {
        attn_ctx<<<BATCH, 1024, 0, stream>>>(
            encProjF, encAHi, encALo, tmp2, V_W, V_b, o2hT, idx, gxHi, gxLo);
        dec_gru3<<<dim3(64, 4), 768, 0, stream>>>(
            (const short8*)hcH, (const short8*)hcL,
            (const short8*)gxHi, (const short8*)gxLo,
            (const short8*)dWrH, (const short8*)dWrL,
            (const short8*)dWzH, (const short8*)dWzL,
            (const short8*)dWnhH, (const short8*)dWnhL,
            (const short8*)dWniH, (const short8*)dWniL,
            dec_bih, dec_bhh, hcF, hnF, hnH, hnL);
        float* pred = out + (size_t)(1 + st) * BATCH * VOUTD;
        fcw2<<<144, 256, 0, stream>>>(
            (const short8*)hnH, (const short8*)hnL,
            (const short8*)fcHi, (const short8*)fcLo,
            fc_b, pred, idx,
            (const short8*)w2Hi, (const short8*)w2Lo, W2_b, tmp2);
        { float* tf = hcF; hcF = hnF; hnF = tf; }
        { short* th = hcH; hcH = hnH; hnH = th; th = hcL; hcL = hnL; hnL = th; }
    }
}

// Round 9
// 3442.597 us; speedup vs baseline: 1.0240x; 1.0240x over previous
//
#include <hip/hip_runtime.h>
#include <math.h>

#define SLEN 64
#define BATCH 256
#define VIND 128
#define VOUTD 128
#define UDIM 1024
#define EDIM 512
#define TDEC 25
#define GXW 1536
#define U3 3072
#define NSEG 12

typedef __attribute__((ext_vector_type(8))) short short8;
typedef __attribute__((ext_vector_type(4))) float f32x4;

#define MFMA(acc, A, B) acc = __builtin_amdgcn_mfma_f32_16x16x32_bf16((A), (B), (acc), 0, 0, 0)

// libm sigmoid/tanh in the RECURRENT path (gates): fast variants drift over the
// 64-step encoder + 24-step decoder recurrence and flip greedy argmax (R1 fail).
__device__ __forceinline__ float sigm(float x) { return 1.f / (1.f + expf(-x)); }

// fast tanh for the attention SCORE path only (non-recurrent-critical)
__device__ __forceinline__ float tanhf_fast(float x) {
    float ax = fabsf(x);
    float e = __expf(-2.f * ax);
    float t = (1.f - e) / (1.f + e);
    return copysignf(t, x);
}

__device__ __forceinline__ short f2bf(float f) {
    unsigned u = __float_as_uint(f);
    u += 0x7FFF + ((u >> 16) & 1);
    return (short)(u >> 16);
}
__device__ __forceinline__ float bf2f(short h) {
    return __uint_as_float(((unsigned)(unsigned short)h) << 16);
}

// fragment-major packed layout for operand X[R][K]:
// chunk(r,k) holds X[r][k..k+8); lane = (r&15) + 16*((k>>3)&3)
__device__ __forceinline__ size_t pkChunk(int r, int k, int K) {
    return ((size_t)(r >> 4) * (K >> 5) + (k >> 5)) * 64 + ((r & 15) + 16 * ((k >> 3) & 3));
}

union S8 { short s[8]; short8 v; };

__device__ __forceinline__ void writeSplit8(short* Hi, short* Lo, size_t chunk,
                                            const float* vals) {
    S8 h, l;
#pragma unroll
    for (int j = 0; j < 8; j++) {
        short hb = f2bf(vals[j]);
        h.s[j] = hb;
        l.s[j] = f2bf(vals[j] - bf2f(hb));
    }
    ((short8*)Hi)[chunk] = h.v;
    ((short8*)Lo)[chunk] = l.v;
}

// ---------------------------------------------------------------------------
__global__ void init_kernel(float* __restrict__ h0, short* __restrict__ hpHi,
                            short* __restrict__ hpLo, float* __restrict__ out0,
                            int* __restrict__ idx,
                            const float* __restrict__ o2h_W,
                            const float* __restrict__ o2h_b,
                            float* __restrict__ o2hT) {
    int i = blockIdx.x * 256 + threadIdx.x;
    if (i < BATCH * UDIM) { h0[i] = 0.f; hpHi[i] = 0; hpLo[i] = 0; }
    if (i < BATCH * VOUTD) out0[i] = ((i & (VOUTD - 1)) == 0) ? 1.f : 0.f;
    if (i < BATCH) idx[i] = 0;
    if (i < VOUTD * EDIM) {
        // o2hT[v][e] = o2h_W[e][v] + o2h_b[e]  (bias folded, row-read at decode)
        int v = i >> 9, e = i & (EDIM - 1);
        o2hT[i] = o2h_W[(size_t)e * VOUTD + v] + o2h_b[e];
    }
}

// ---------------------------------------------------------------------------
// All weight/input packing in ONE kernel: segment table passed by value.
// ---------------------------------------------------------------------------
struct PackSeg {
    const float* sA; const float* sB;
    short* Hi; short* Lo;
    int KA, KB, offA, offB, chunkStart;
};
struct PackArgs { PackSeg s[NSEG]; };

__global__ void pack_all(PackArgs pa, int total) {
    int gid = blockIdx.x * 256 + threadIdx.x;
    if (gid >= total) return;
    int si = 0;
#pragma unroll
    for (int i = 1; i < NSEG; i++) si = (gid >= pa.s[i].chunkStart) ? i : si;
    PackSeg sg = pa.s[si];
    int local = gid - sg.chunkStart;
    int K = sg.KA + sg.KB;
    int cpr = K >> 3;
    int r = local / cpr, k0 = (local - r * cpr) * 8;
    const float* src = (k0 < sg.KA)
        ? sg.sA + (size_t)(sg.offA + r) * sg.KA + k0
        : sg.sB + (size_t)(sg.offB + r) * sg.KB + (k0 - sg.KA);
    float v[8];
#pragma unroll
    for (int j = 0; j < 8; j++) v[j] = src[j];
    writeSplit8(sg.Hi, sg.Lo, pkChunk(r, k0, K), v);
}

// ---------------------------------------------------------------------------
// Split-bf16 3-pass MFMA GEMM, BM=64 x BN=128 block (4 waves of 32x64).
// ---------------------------------------------------------------------------
__global__ __launch_bounds__(256) void gemm_w(
    const short8* __restrict__ Ahi, const short8* __restrict__ Alo,
    const short8* __restrict__ Whi, const short8* __restrict__ Wlo,
    const float* __restrict__ bias, float* __restrict__ C,
    int KT, int N) {
    int tid = threadIdx.x, lane = tid & 63, wave = tid >> 6;
    int m16 = blockIdx.x * 4 + (wave & 1) * 2;
    int nb = blockIdx.y * 8 + (wave >> 1) * 4;
    const short8* a0h = Ahi + (size_t)m16 * KT * 64 + lane;
    const short8* a1h = a0h + (size_t)KT * 64;
    const short8* a0l = Alo + (size_t)m16 * KT * 64 + lane;
    const short8* a1l = a0l + (size_t)KT * 64;
    const short8* w0h = Whi + (size_t)(nb + 0) * KT * 64 + lane;
    const short8* w1h = Whi + (size_t)(nb + 1) * KT * 64 + lane;
    const short8* w2h = Whi + (size_t)(nb + 2) * KT * 64 + lane;
    const short8* w3h = Whi + (size_t)(nb + 3) * KT * 64 + lane;
    const short8* w0l = Wlo + (size_t)(nb + 0) * KT * 64 + lane;
    const short8* w1l = Wlo + (size_t)(nb + 1) * KT * 64 + lane;
    const short8* w2l = Wlo + (size_t)(nb + 2) * KT * 64 + lane;
    const short8* w3l = Wlo + (size_t)(nb + 3) * KT * 64 + lane;
    f32x4 acc0[4] = {}, acc1[4] = {};

    for (int kt = 0; kt < KT; kt++) {
        size_t o = (size_t)kt * 64;
        short8 A0H = a0h[o], A1H = a1h[o], A0L = a0l[o], A1L = a1l[o];
        short8 WH0 = w0h[o], WL0 = w0l[o];
        MFMA(acc0[0], A0H, WH0); MFMA(acc1[0], A1H, WH0);
        MFMA(acc0[0], A0H, WL0); MFMA(acc1[0], A1H, WL0);
        MFMA(acc0[0], A0L, WH0); MFMA(acc1[0], A1L, WH0);
        short8 WH1 = w1h[o], WL1 = w1l[o];
        MFMA(acc0[1], A0H, WH1); MFMA(acc1[1], A1H, WH1);
        MFMA(acc0[1], A0H, WL1); MFMA(acc1[1], A1H, WL1);
        MFMA(acc0[1], A0L, WH1); MFMA(acc1[1], A1L, WH1);
        short8 WH2 = w2h[o], WL2 = w2l[o];
        MFMA(acc0[2], A0H, WH2); MFMA(acc1[2], A1H, WH2);
        MFMA(acc0[2], A0H, WL2); MFMA(acc1[2], A1H, WL2);
        MFMA(acc0[2], A0L, WH2); MFMA(acc1[2], A1L, WH2);
        short8 WH3 = w3h[o], WL3 = w3l[o];
        MFMA(acc0[3], A0H, WH3); MFMA(acc1[3], A1H, WH3);
        MFMA(acc0[3], A0H, WL3); MFMA(acc1[3], A1H, WL3);
        MFMA(acc0[3], A0L, WH3); MFMA(acc1[3], A1L, WH3);
    }
    int rsub = (lane >> 4) * 4, cn = lane & 15;
    int row0 = (m16 + 0) * 16 + rsub;
    int row1 = (m16 + 1) * 16 + rsub;
#pragma unroll
    for (int j = 0; j < 4; j++) {
        int col = (nb + j) * 16 + cn;
        float bb = bias ? bias[col] : 0.f;
#pragma unroll
        for (int r = 0; r < 4; r++) {
            C[(size_t)(row0 + r) * N + col] = acc0[j][r] + bb;
            C[(size_t)(row1 + r) * N + col] = acc1[j][r] + bb;
        }
    }
}

// ---------------------------------------------------------------------------
// BM=32 GEMM for the pre-loop tmp2. Grid (M/32, N/64).
// ---------------------------------------------------------------------------
__global__ __launch_bounds__(256) void gemm_bm32(
    const short8* __restrict__ Ahi, const short8* __restrict__ Alo,
    const short8* __restrict__ Whi, const short8* __restrict__ Wlo,
    const float* __restrict__ bias, float* __restrict__ C,
    int KT, int N) {
    int tid = threadIdx.x, lane = tid & 63, wave = tid >> 6;
    int m16 = blockIdx.x * 2 + (wave & 1);
    int n16 = blockIdx.y * 4 + (wave >> 1) * 2;
    const short8* ah = Ahi + (size_t)m16 * KT * 64 + lane;
    const short8* al = Alo + (size_t)m16 * KT * 64 + lane;
    const short8* w0h = Whi + (size_t)n16 * KT * 64 + lane;
    const short8* w1h = w0h + (size_t)KT * 64;
    const short8* w0l = Wlo + (size_t)n16 * KT * 64 + lane;
    const short8* w1l = w0l + (size_t)KT * 64;
    f32x4 a0 = {0,0,0,0}, a1 = {0,0,0,0};
    for (int kt = 0; kt < KT; kt++) {
        size_t o = (size_t)kt * 64;
        short8 AH = ah[o], AL = al[o];
        short8 W0H = w0h[o], W0L = w0l[o], W1H = w1h[o], W1L = w1l[o];
        MFMA(a0, AH, W0H); MFMA(a1, AH, W1H);
        MFMA(a0, AH, W0L); MFMA(a1, AH, W1L);
        MFMA(a0, AL, W0H); MFMA(a1, AL, W1H);
    }
    int rsub = (lane >> 4) * 4, cn = lane & 15;
    float b0 = bias ? bias[(n16 + 0) * 16 + cn] : 0.f;
    float b1 = bias ? bias[(n16 + 1) * 16 + cn] : 0.f;
#pragma unroll
    for (int r = 0; r < 4; r++) {
        int row = m16 * 16 + rsub + r;
        C[(size_t)row * N + (n16 + 0) * 16 + cn] = a0[r] + b0;
        C[(size_t)row * N + (n16 + 1) * 16 + cn] = a1[r] + b1;
    }
}

// ---------------------------------------------------------------------------
// Encoder GRU step: 12 waves = (gate x K-half x m-pair); block covers FOUR
// m16 tiles (R6 structure — best known). Grid (64, 4), 12 waves/CU.
// gi is a 16-step chunk buffer: row = (t & 15)*256 + b.
// ---------------------------------------------------------------------------
__global__ __launch_bounds__(768) void enc_gru3(
    const short8* __restrict__ hinH8, const short8* __restrict__ hinL8,
    const short8* __restrict__ WrH, const short8* __restrict__ WrL,
    const short8* __restrict__ WzH, const short8* __restrict__ WzL,
    const short8* __restrict__ WnH, const short8* __restrict__ WnL,
    const float* __restrict__ gi,
    const float* __restrict__ bih, const float* __restrict__ bhh,
    const float* __restrict__ hinF, float* __restrict__ houtF,
    short* __restrict__ hoH, short* __restrict__ hoL,
    short* __restrict__ eaHi, short* __restrict__ eaLo,
    const int* __restrict__ x_len, int t) {
    __shared__ float sC[6][4][16][16];
    __shared__ float sHo[4][16][16];
    __shared__ float sEo[4][16][16];
    int tid = threadIdx.x, lane = tid & 63, wave = tid >> 6;  // wave 0..11
    int g = blockIdx.x;
    int m16a = blockIdx.y * 4;
    int gate = wave >> 2, hm = wave & 3, half = hm >> 1, mp = hm & 1;
    int t0 = mp * 2;  // this wave's tiles: t0, t0+1
    const short8* a0h = hinH8 + (size_t)(m16a + t0) * 32 * 64 + (size_t)half * 16 * 64 + lane;
    const short8* a0l = hinL8 + (size_t)(m16a + t0) * 32 * 64 + (size_t)half * 16 * 64 + lane;
    const short8* a1h = a0h + (size_t)32 * 64;
    const short8* a1l = a0l + (size_t)32 * 64;
    const short8* WH0 = (gate == 0) ? WrH : (gate == 1) ? WzH : WnH;
    const short8* WL0 = (gate == 0) ? WrL : (gate == 1) ? WzL : WnL;
    const short8* wh = WH0 + (size_t)g * 32 * 64 + (size_t)half * 16 * 64 + lane;
    const short8* wl = WL0 + (size_t)g * 32 * 64 + (size_t)half * 16 * 64 + lane;
    f32x4 acc0 = {0, 0, 0, 0}, acc1 = {0, 0, 0, 0};
    for (int kt = 0; kt < 16; kt++) {
        size_t o = (size_t)kt * 64;
        short8 WH = wh[o], WL = wl[o];
        short8 A0H = a0h[o], A0L = a0l[o];
        MFMA(acc0, A0H, WH); MFMA(acc0, A0H, WL); MFMA(acc0, A0L, WH);
        short8 A1H = a1h[o], A1L = a1l[o];
        MFMA(acc1, A1H, WH); MFMA(acc1, A1H, WL); MFMA(acc1, A1L, WH);
    }
    {
        int slot = gate * 2 + half;
        int rsub = (lane >> 4) << 2, cn = lane & 15;
#pragma unroll
        for (int j = 0; j < 4; j++) {
            sC[slot][t0 + 0][rsub + j][cn] = acc0[j];
            sC[slot][t0 + 1][rsub + j][cn] = acc1[j];
        }
    }
    __syncthreads();
    if (wave < 4) {
        int tile = wave;
        int m16 = m16a + tile;
        int cu = g * 16 + (lane & 15);
        int rsub = (lane >> 4) << 2;
        float b_r = bih[cu] + bhh[cu];
        float b_z = bih[UDIM + cu] + bhh[UDIM + cu];
        float b_nh = bhh[2 * UDIM + cu];
        float b_ni = bih[2 * UDIM + cu];
        int growLocal = (t & 15) * 256;
#pragma unroll
        for (int j = 0; j < 4; j++) {
            int rr = rsub + j, cc = lane & 15;
            int b = m16 * 16 + rr;
            const float* gr = gi + (size_t)(growLocal + b) * U3;
            float rg = sigm(sC[0][tile][rr][cc] + sC[1][tile][rr][cc] + gr[cu] + b_r);
            float zg = sigm(sC[2][tile][rr][cc] + sC[3][tile][rr][cc] + gr[UDIM + cu] + b_z);
            float nn = tanhf(gr[2 * UDIM + cu] + b_ni +
                             rg * (sC[4][tile][rr][cc] + sC[5][tile][rr][cc] + b_nh));
            float hp = hinF[(size_t)b * UDIM + cu];
            float hv = (1.f - zg) * nn + zg * hp;
            bool msk = t < x_len[b];
            float ho = msk ? hv : hp;
            houtF[(size_t)b * UDIM + cu] = ho;
            sHo[tile][rr][cc] = ho;
            sEo[tile][rr][cc] = msk ? hv : 0.f;
        }
    }
    __syncthreads();
    if (wave >= 4 && wave < 8 && lane < 32) {
        int tile = wave - 4;
        int m16 = m16a + tile;
        int rr = lane >> 1, oct = lane & 1;
        int brow = m16 * 16 + rr;
        int u0 = g * 16 + oct * 8;
        float v[8];
#pragma unroll
        for (int j = 0; j < 8; j++) v[j] = sHo[tile][rr][oct * 8 + j];
        writeSplit8(hoH, hoL, pkChunk(brow, u0, UDIM), v);
#pragma unroll
        for (int j = 0; j < 8; j++) v[j] = sEo[tile][rr][oct * 8 + j];
        writeSplit8(eaHi, eaLo, pkChunk(brow * SLEN + t, u0, UDIM), v);
    }
}

// ---------------------------------------------------------------------------
// Decoder GRU step: 12 waves = (gate x K-half x m-pair); block covers FOUR
// m16 tiles (R6 structure — best known). Grid (64, 4).
// ---------------------------------------------------------------------------
__global__ __launch_bounds__(768) void dec_gru3(
    const short8* __restrict__ hinH8, const short8* __restrict__ hinL8,
    const short8* __restrict__ gxH8, const short8* __restrict__ gxL8,
    const short8* __restrict__ WrH, const short8* __restrict__ WrL,
    const short8* __restrict__ WzH, const short8* __restrict__ WzL,
    const short8* __restrict__ WnhH, const short8* __restrict__ WnhL,
    const short8* __restrict__ WniH, const short8* __restrict__ WniL,
    const float* __restrict__ bih, const float* __restrict__ bhh,
    const float* __restrict__ hinF, float* __restrict__ houtF,
    short* __restrict__ hoH, short* __restrict__ hoL) {
    __shared__ float sC[8][4][16][16];
    __shared__ float sHo[4][16][16];
    int tid = threadIdx.x, lane = tid & 63, wave = tid >> 6;  // 0..11
    int g = blockIdx.x;
    int m16a = blockIdx.y * 4;
    int gate = wave >> 2, hm = wave & 3, half = hm >> 1, mp = hm & 1;
    int t0 = mp * 2;
    const short8* a0h = hinH8 + (size_t)(m16a + t0) * 32 * 64 + (size_t)half * 16 * 64 + lane;
    const short8* a0l = hinL8 + (size_t)(m16a + t0) * 32 * 64 + (size_t)half * 16 * 64 + lane;
    const short8* a1h = a0h + (size_t)32 * 64;
    const short8* a1l = a0l + (size_t)32 * 64;
    const short8* g0h = gxH8 + (size_t)(m16a + t0) * 48 * 64 + (size_t)half * 24 * 64 + lane;
    const short8* g0l = gxL8 + (size_t)(m16a + t0) * 48 * 64 + (size_t)half * 24 * 64 + lane;
    const short8* g1h = g0h + (size_t)48 * 64;
    const short8* g1l = g0l + (size_t)48 * 64;
    const short8 *whA, *wlA, *whB, *wlB;
    if (gate == 0) {
        whA = WrH + (size_t)g * 80 * 64 + (size_t)half * 16 * 64 + lane;
        wlA = WrL + (size_t)g * 80 * 64 + (size_t)half * 16 * 64 + lane;
        whB = WrH + (size_t)g * 80 * 64 + (size_t)(32 + half * 24) * 64 + lane;
        wlB = WrL + (size_t)g * 80 * 64 + (size_t)(32 + half * 24) * 64 + lane;
    } else if (gate == 1) {
        whA = WzH + (size_t)g * 80 * 64 + (size_t)half * 16 * 64 + lane;
        wlA = WzL + (size_t)g * 80 * 64 + (size_t)half * 16 * 64 + lane;
        whB = WzH + (size_t)g * 80 * 64 + (size_t)(32 + half * 24) * 64 + lane;
        wlB = WzL + (size_t)g * 80 * 64 + (size_t)(32 + half * 24) * 64 + lane;
    } else {
        whA = WnhH + (size_t)g * 32 * 64 + (size_t)half * 16 * 64 + lane;
        wlA = WnhL + (size_t)g * 32 * 64 + (size_t)half * 16 * 64 + lane;
        whB = WniH + (size_t)g * 48 * 64 + (size_t)half * 24 * 64 + lane;
        wlB = WniL + (size_t)g * 48 * 64 + (size_t)half * 24 * 64 + lane;
    }
    f32x4 accA0 = {0,0,0,0}, accA1 = {0,0,0,0};
    f32x4 accB0 = {0,0,0,0}, accB1 = {0,0,0,0};
    for (int kt = 0; kt < 16; kt++) {
        size_t o = (size_t)kt * 64;
        short8 WH = whA[o], WL = wlA[o];
        short8 A0H = a0h[o], A0L = a0l[o];
        MFMA(accA0, A0H, WH); MFMA(accA0, A0H, WL); MFMA(accA0, A0L, WH);
        short8 A1H = a1h[o], A1L = a1l[o];
        MFMA(accA1, A1H, WH); MFMA(accA1, A1H, WL); MFMA(accA1, A1L, WH);
    }
    for (int kt = 0; kt < 24; kt++) {
        size_t o = (size_t)kt * 64;
        short8 WH = whB[o], WL = wlB[o];
        short8 G0H = g0h[o], G0L = g0l[o];
        MFMA(accB0, G0H, WH); MFMA(accB0, G0H, WL); MFMA(accB0, G0L, WH);
        short8 G1H = g1h[o], G1L = g1l[o];
        MFMA(accB1, G1H, WH); MFMA(accB1, G1H, WL); MFMA(accB1, G1L, WH);
    }
    {
        int rsub = (lane >> 4) << 2, cn = lane & 15;
        if (gate < 2) {
            int slot = gate * 2 + half;
#pragma unroll
            for (int j = 0; j < 4; j++) {
                sC[slot][t0 + 0][rsub + j][cn] = accA0[j] + accB0[j];
                sC[slot][t0 + 1][rsub + j][cn] = accA1[j] + accB1[j];
            }
        } else {
#pragma unroll
            for (int j = 0; j < 4; j++) {
                sC[4 + half][t0 + 0][rsub + j][cn] = accA0[j];  // nh
                sC[4 + half][t0 + 1][rsub + j][cn] = accA1[j];
                sC[6 + half][t0 + 0][rsub + j][cn] = accB0[j];  // ni
                sC[6 + half][t0 + 1][rsub + j][cn] = accB1[j];
            }
        }
    }
    __syncthreads();
    if (wave < 4) {
        int tile = wave;
        int m16 = m16a + tile;
        int cu = g * 16 + (lane & 15);
        int rsub = (lane >> 4) << 2;
        float b_r = bih[cu] + bhh[cu];
        float b_z = bih[UDIM + cu] + bhh[UDIM + cu];
        float b_nh = bhh[2 * UDIM + cu];
        float b_ni = bih[2 * UDIM + cu];
#pragma unroll
        for (int j = 0; j < 4; j++) {
            int rr = rsub + j, cc = lane & 15;
            int b = m16 * 16 + rr;
            float rg = sigm(sC[0][tile][rr][cc] + sC[1][tile][rr][cc] + b_r);
            float zg = sigm(sC[2][tile][rr][cc] + sC[3][tile][rr][cc] + b_z);
            float nn = tanhf(sC[6][tile][rr][cc] + sC[7][tile][rr][cc] + b_ni +
                             rg * (sC[4][tile][rr][cc] + sC[5][tile][rr][cc] + b_nh));
            float hp = hinF[(size_t)b * UDIM + cu];
            float hv = (1.f - zg) * nn + zg * hp;
            houtF[(size_t)b * UDIM + cu] = hv;
            sHo[tile][rr][cc] = hv;
        }
    }
    __syncthreads();
    if (wave >= 4 && wave < 8 && lane < 32) {
        int tile = wave - 4;
        int m16 = m16a + tile;
        int rr = lane >> 1, oct = lane & 1;
        int brow = m16 * 16 + rr;
        int u0 = g * 16 + oct * 8;
        float v[8];
#pragma unroll
        for (int j = 0; j < 8; j++) v[j] = sHo[tile][rr][oct * 8 + j];
        writeSplit8(hoH, hoL, pkChunk(brow, u0, UDIM), v);
    }
}

// ---------------------------------------------------------------------------
// Attention + ctx + emb -> gx split-pack. 1024-thread blocks (16 waves/CU):
// score pass 16-wave s-stride; ctx pass 8-way s-split with LDS combine;
// emb reads pre-transposed bias-folded o2hT row (coalesced).
// ---------------------------------------------------------------------------
__global__ __launch_bounds__(1024) void attn_ctx(
    const float* __restrict__ encProj,
    const short* __restrict__ eaHi, const short* __restrict__ eaLo,
    const float* __restrict__ tmp2, const float* __restrict__ V_W,
    const float* __restrict__ V_b,
    const float* __restrict__ o2hT,
    const int* __restrict__ idx, short* __restrict__ gxHi, short* __restrict__ gxLo) {
    int b = blockIdx.x;
    int tid = threadIdx.x, lane = tid & 63, wave = tid >> 6;
    __shared__ float s_t2[UDIM];
    __shared__ float s_v[UDIM];
    __shared__ float s_attn[SLEN];
    __shared__ float s_part[7][128][9];  // pad 9 floats: conflict-free combine
    for (int u = tid; u < UDIM; u += 1024) {
        s_t2[u] = tmp2[(size_t)b * UDIM + u];
        s_v[u] = V_W[u];
    }
    __syncthreads();
    for (int s = wave; s < SLEN; s += 16) {
        const float4* ep4 = (const float4*)(encProj + ((size_t)b * SLEN + s) * UDIM);
        float p = 0.f;
        for (int u4 = lane; u4 < UDIM / 4; u4 += 64) {
            float4 e = ep4[u4];
            int u = 4 * u4;
            p += tanhf_fast(e.x + s_t2[u]) * s_v[u] +
                 tanhf_fast(e.y + s_t2[u + 1]) * s_v[u + 1] +
                 tanhf_fast(e.z + s_t2[u + 2]) * s_v[u + 2] +
                 tanhf_fast(e.w + s_t2[u + 3]) * s_v[u + 3];
        }
#pragma unroll
        for (int off = 32; off > 0; off >>= 1) p += __shfl_xor(p, off);
        if (lane == 0) s_attn[s] = p + V_b[0];
    }
    __syncthreads();
    if (tid < 64) {
        float v = s_attn[tid];
        float mx = v;
#pragma unroll
        for (int off = 32; off > 0; off >>= 1) mx = fmaxf(mx, __shfl_xor(mx, off));
        float e = expf(v - mx);
        float sum = e;
#pragma unroll
        for (int off = 32; off > 0; off >>= 1) sum += __shfl_xor(sum, off);
        s_attn[tid] = e / sum;
    }
    __syncthreads();
    {
        int grp = tid >> 7, tu = tid & 127;  // 8 s-groups x 128 u-threads
        int u0 = tu * 8;
        float a[8] = {0, 0, 0, 0, 0, 0, 0, 0};
        const short8* hi8 = (const short8*)eaHi;
        const short8* lo8 = (const short8*)eaLo;
        int lanePart = 16 * ((u0 >> 3) & 3);
        int colPart = u0 >> 5;
        for (int s = grp * 8; s < grp * 8 + 8; s++) {
            int r = b * SLEN + s;
            size_t ch = ((size_t)(r >> 4) * (UDIM >> 5) + colPart) * 64 + (r & 15) + lanePart;
            S8 h, l;
            h.v = hi8[ch];
            l.v = lo8[ch];
            float w = s_attn[s];
#pragma unroll
            for (int j = 0; j < 8; j++) a[j] += w * (bf2f(h.s[j]) + bf2f(l.s[j]));
        }
        if (grp) {
#pragma unroll
            for (int j = 0; j < 8; j++) s_part[grp - 1][tu][j] = a[j];
        }
        __syncthreads();
        if (tid < 128) {
#pragma unroll
            for (int gg = 0; gg < 7; gg++)
#pragma unroll
                for (int j = 0; j < 8; j++) a[j] += s_part[gg][tu][j];
            writeSplit8(gxHi, gxLo, pkChunk(b, u0, GXW), a);
        } else if (tid < 192) {
            int e0 = (tid - 128) * 8;
            int ib = idx[b];
            const float* row = o2hT + (size_t)ib * EDIM + e0;
            float v[8];
#pragma unroll
            for (int j = 0; j < 8; j++) v[j] = row[j];
            writeSplit8(gxHi, gxLo, pkChunk(b, UDIM + e0, GXW), v);
        }
    }
}

// ---------------------------------------------------------------------------
// Merged: pred=h@fc^T+b + parallel first-max argmax (blocks 0..15) AND
// tmp2=h@W2^T+b for the next step (blocks 16..143). Final decode step
// launches only 16 blocks (tmp2 dead).
// ---------------------------------------------------------------------------
__global__ __launch_bounds__(256) void fcw2(
    const short8* __restrict__ hHi, const short8* __restrict__ hLo,
    const short8* __restrict__ fcH, const short8* __restrict__ fcL,
    const float* __restrict__ fc_b, float* __restrict__ pred,
    int* __restrict__ idx,
    const short8* __restrict__ w2H, const short8* __restrict__ w2L,
    const float* __restrict__ W2_b, float* __restrict__ tmp2) {
    __shared__ float sP[16][129];
    int tid = threadIdx.x, lane = tid & 63, wave = tid >> 6;
    if (blockIdx.x < 16) {
        int fm = blockIdx.x;
        const short8* ah = hHi + (size_t)fm * 32 * 64 + lane;
        const short8* al = hLo + (size_t)fm * 32 * 64 + lane;
        int n0 = 2 * wave, n1 = 2 * wave + 1;
        const short8* w0h = fcH + (size_t)n0 * 32 * 64 + lane;
        const short8* w0l = fcL + (size_t)n0 * 32 * 64 + lane;
        const short8* w1h = fcH + (size_t)n1 * 32 * 64 + lane;
        const short8* w1l = fcL + (size_t)n1 * 32 * 64 + lane;
        f32x4 a0 = {0,0,0,0}, a1 = {0,0,0,0};
        for (int kt = 0; kt < 32; kt++) {
            size_t o = (size_t)kt * 64;
            short8 AH = ah[o], AL = al[o];
            short8 W0H = w0h[o], W0L = w0l[o], W1H = w1h[o], W1L = w1l[o];
            MFMA(a0, AH, W0H); MFMA(a1, AH, W1H);
            MFMA(a0, AH, W0L); MFMA(a1, AH, W1L);
            MFMA(a0, AL, W0H); MFMA(a1, AL, W1H);
        }
        int cn = lane & 15, rsub = (lane >> 4) << 2;
#pragma unroll
        for (int j = 0; j < 4; j++) {
            sP[rsub + j][n0 * 16 + cn] = a0[j] + fc_b[n0 * 16 + cn];
            sP[rsub + j][n1 * 16 + cn] = a1[j] + fc_b[n1 * 16 + cn];
        }
        __syncthreads();
        {
            int row = tid >> 4, c0 = (tid & 15) * 8;
            float* pr = pred + (size_t)(fm * 16 + row) * VOUTD;
#pragma unroll
            for (int j = 0; j < 8; j++) pr[c0 + j] = sP[row][c0 + j];
        }
        if (tid < 128) {
            // 8 lanes per row, first-max semantics (strict > in scan order,
            // smaller index wins ties across segments)
            int row = tid >> 3, seg = tid & 7;
            float v = -1e30f;
            int bi = 0;
            int c0 = seg * 16;
            for (int j = c0; j < c0 + 16; j++) {
                float w = sP[row][j];
                if (w > v) { v = w; bi = j; }
            }
#pragma unroll
            for (int off = 1; off < 8; off <<= 1) {
                float ov = __shfl_xor(v, off);
                int obi = __shfl_xor(bi, off);
                if (ov > v || (ov == v && obi < bi)) { v = ov; bi = obi; }
            }
            if (seg == 0) idx[fm * 16 + row] = bi;
        }
    } else {
        int lin = blockIdx.x - 16;       // 0..127
        int bx = lin & 7, by = lin >> 3; // bm32 grid (8, 16)
        int m16 = bx * 2 + (wave & 1);
        int n16 = by * 4 + (wave >> 1) * 2;
        const short8* ah = hHi + (size_t)m16 * 32 * 64 + lane;
        const short8* al = hLo + (size_t)m16 * 32 * 64 + lane;
        const short8* w0h = w2H + (size_t)n16 * 32 * 64 + lane;
        const short8* w1h = w0h + (size_t)32 * 64;
        const short8* w0l = w2L + (size_t)n16 * 32 * 64 + lane;
        const short8* w1l = w0l + (size_t)32 * 64;
        f32x4 a0 = {0,0,0,0}, a1 = {0,0,0,0};
        for (int kt = 0; kt < 32; kt++) {
            size_t o = (size_t)kt * 64;
            short8 AH = ah[o], AL = al[o];
            short8 W0H = w0h[o], W0L = w0l[o], W1H = w1h[o], W1L = w1l[o];
            MFMA(a0, AH, W0H); MFMA(a1, AH, W1H);
            MFMA(a0, AH, W0L); MFMA(a1, AH, W1L);
            MFMA(a0, AL, W0H); MFMA(a1, AL, W1H);
        }
        int rsub = (lane >> 4) * 4, cn = lane & 15;
        float b0 = W2_b[(n16 + 0) * 16 + cn];
        float b1 = W2_b[(n16 + 1) * 16 + cn];
#pragma unroll
        for (int r = 0; r < 4; r++) {
            int row = m16 * 16 + rsub + r;
            tmp2[(size_t)row * UDIM + (n16 + 0) * 16 + cn] = a0[r] + b0;
            tmp2[(size_t)row * UDIM + (n16 + 1) * 16 + cn] = a1[r] + b1;
        }
    }
}

// ---------------------------------------------------------------------------
extern "C" void kernel_launch(void* const* d_in, const int* in_sizes, int n_in,
                              void* d_out, int out_size, void* d_ws, size_t ws_size,
                              hipStream_t stream) {
    const float* x       = (const float*)d_in[0];
    const int*   x_len   = (const int*)d_in[1];
    const float* enc_Wih = (const float*)d_in[2];
    const float* enc_Whh = (const float*)d_in[3];
    const float* enc_bih = (const float*)d_in[4];
    const float* enc_bhh = (const float*)d_in[5];
    const float* dec_Wih = (const float*)d_in[6];
    const float* dec_Whh = (const float*)d_in[7];
    const float* dec_bih = (const float*)d_in[8];
    const float* dec_bhh = (const float*)d_in[9];
    const float* o2h_W   = (const float*)d_in[10];
    const float* o2h_b   = (const float*)d_in[11];
    const float* fc_W    = (const float*)d_in[12];
    const float* fc_b    = (const float*)d_in[13];
    const float* W1_W    = (const float*)d_in[14];
    const float* W1_b    = (const float*)d_in[15];
    const float* W2_W    = (const float*)d_in[16];
    const float* W2_b    = (const float*)d_in[17];
    const float* V_W     = (const float*)d_in[18];
    const float* V_b     = (const float*)d_in[19];
    float* out = (float*)d_out;

    char* p = (char*)d_ws;
    auto alloc = [&](size_t bytes) -> char* {
        char* q = p;
        p += (bytes + 255) & ~(size_t)255;
        return q;
    };
    float* hAF  = (float*)alloc((size_t)BATCH * UDIM * 4);
    float* hBF  = (float*)alloc((size_t)BATCH * UDIM * 4);
    short* hAH  = (short*)alloc((size_t)BATCH * UDIM * 2);
    short* hAL  = (short*)alloc((size_t)BATCH * UDIM * 2);
    short* hBH  = (short*)alloc((size_t)BATCH * UDIM * 2);
    short* hBL  = (short*)alloc((size_t)BATCH * UDIM * 2);
    float* tmp2 = (float*)alloc((size_t)BATCH * UDIM * 4);
    short* gxHi = (short*)alloc((size_t)BATCH * GXW * 2);
    short* gxLo = (short*)alloc((size_t)BATCH * GXW * 2);
    short* encAHi = (short*)alloc((size_t)BATCH * SLEN * UDIM * 2);
    short* encALo = (short*)alloc((size_t)BATCH * SLEN * UDIM * 2);
    // encProj region (67 MB) doubles as the gi 16-step chunk buffer (50 MB):
    // gi chunks are dead before enc_proj is written. Zero extra workspace.
    float* encProjF = (float*)alloc((size_t)BATCH * SLEN * UDIM * 4);
    float* gihBuf = encProjF;
    short* eWihH = (short*)alloc((size_t)U3 * VIND * 2);
    short* eWihL = (short*)alloc((size_t)U3 * VIND * 2);
    short* eWrH = (short*)alloc((size_t)UDIM * UDIM * 2);
    short* eWrL = (short*)alloc((size_t)UDIM * UDIM * 2);
    short* eWzH = (short*)alloc((size_t)UDIM * UDIM * 2);
    short* eWzL = (short*)alloc((size_t)UDIM * UDIM * 2);
    short* eWnH = (short*)alloc((size_t)UDIM * UDIM * 2);
    short* eWnL = (short*)alloc((size_t)UDIM * UDIM * 2);
    short* dWrH = (short*)alloc((size_t)UDIM * 2560 * 2);
    short* dWrL = (short*)alloc((size_t)UDIM * 2560 * 2);
    short* dWzH = (short*)alloc((size_t)UDIM * 2560 * 2);
    short* dWzL = (short*)alloc((size_t)UDIM * 2560 * 2);
    short* dWnhH = (short*)alloc((size_t)UDIM * UDIM * 2);
    short* dWnhL = (short*)alloc((size_t)UDIM * UDIM * 2);
    short* dWniH = (short*)alloc((size_t)UDIM * GXW * 2);
    short* dWniL = (short*)alloc((size_t)UDIM * GXW * 2);
    short* w1Hi = (short*)alloc((size_t)UDIM * UDIM * 2);
    short* w1Lo = (short*)alloc((size_t)UDIM * UDIM * 2);
    short* w2Hi = (short*)alloc((size_t)UDIM * UDIM * 2);
    short* w2Lo = (short*)alloc((size_t)UDIM * UDIM * 2);
    short* fcHi = (short*)alloc((size_t)VOUTD * UDIM * 2);
    short* fcLo = (short*)alloc((size_t)VOUTD * UDIM * 2);
    short* xHi  = (short*)alloc((size_t)SLEN * BATCH * VIND * 2);
    short* xLo  = (short*)alloc((size_t)SLEN * BATCH * VIND * 2);
    int*   idx  = (int*)alloc(BATCH * 4);
    float* o2hT = (float*)alloc((size_t)VOUTD * EDIM * 4);

    init_kernel<<<(BATCH * UDIM + 255) / 256, 256, 0, stream>>>(
        hAF, hAH, hAL, out, idx, o2h_W, o2h_b, o2hT);

    // ---- single packing kernel for all weights + x ----
    {
        PackArgs pa;
        int cs = 0, n = 0;
        auto seg = [&](const float* sA, int KA, int offA, const float* sB, int KB,
                       int offB, short* Hi, short* Lo, int R) {
            pa.s[n] = {sA, sB, Hi, Lo, KA, KB, offA, offB, cs};
            cs += R * (KA + KB) / 8;
            n++;
        };
        seg(enc_Wih, VIND, 0, nullptr, 0, 0, eWihH, eWihL, U3);
        seg(enc_Whh, UDIM, 0, nullptr, 0, 0, eWrH, eWrL, UDIM);
        seg(enc_Whh, UDIM, UDIM, nullptr, 0, 0, eWzH, eWzL, UDIM);
        seg(enc_Whh, UDIM, 2 * UDIM, nullptr, 0, 0, eWnH, eWnL, UDIM);
        seg(dec_Whh, UDIM, 0, dec_Wih, GXW, 0, dWrH, dWrL, UDIM);
        seg(dec_Whh, UDIM, UDIM, dec_Wih, GXW, UDIM, dWzH, dWzL, UDIM);
        seg(dec_Whh, UDIM, 2 * UDIM, nullptr, 0, 0, dWnhH, dWnhL, UDIM);
        seg(dec_Wih, GXW, 2 * UDIM, nullptr, 0, 0, dWniH, dWniL, UDIM);
        seg(W1_W, UDIM, 0, nullptr, 0, 0, w1Hi, w1Lo, UDIM);
        seg(W2_W, UDIM, 0, nullptr, 0, 0, w2Hi, w2Lo, UDIM);
        seg(fc_W, UDIM, 0, nullptr, 0, 0, fcHi, fcLo, VOUTD);
        seg(x, VIND, 0, nullptr, 0, 0, xHi, xLo, SLEN * BATCH);
        pack_all<<<(cs + 255) / 256, 256, 0, stream>>>(pa, cs);
    }

    // ---- encoder: 4 chunks of (16-step gi GEMM + 16 fused GRU steps) ----
    float* hcF = hAF; float* hnF = hBF;
    short *hcH = hAH, *hcL = hAL, *hnH = hBH, *hnL = hBL;
    for (int c = 0; c < 4; c++) {
        // chunk GEMM: M = 16*256 = 4096 rows of x -> gi chunk
        gemm_w<<<dim3(64, 24), 256, 0, stream>>>(
            (const short8*)xHi + (size_t)c * 256 * 4 * 64,
            (const short8*)xLo + (size_t)c * 256 * 4 * 64,
            (const short8*)eWihH, (const short8*)eWihL,
            nullptr, gihBuf, VIND / 32, U3);
        for (int tt = 0; tt < 16; tt++) {
            int t = c * 16 + tt;
            enc_gru3<<<dim3(64, 4), 768, 0, stream>>>(
                (const short8*)hcH, (const short8*)hcL,
                (const short8*)eWrH, (const short8*)eWrL,
                (const short8*)eWzH, (const short8*)eWzL,
                (const short8*)eWnH, (const short8*)eWnL,
                gihBuf, enc_bih, enc_bhh, hcF, hnF, hnH, hnL,
                encAHi, encALo, x_len, t);
            { float* tf = hcF; hcF = hnF; hnF = tf; }
            { short* th = hcH; hcH = hnH; hnH = th; th = hcL; hcL = hnL; hnL = th; }
        }
    }

    // ---- enc_proj = enc_out @ W1^T + W1_b (overwrites gi chunk region) ----
    gemm_w<<<dim3(SLEN * BATCH / 64, UDIM / 128), 256, 0, stream>>>(
        (const short8*)encAHi, (const short8*)encALo,
        (const short8*)w1Hi, (const short8*)w1Lo,
        W1_b, encProjF, UDIM / 32, UDIM);

    // ---- initial tmp2 from encoder hidden ----
    gemm_bm32<<<dim3(BATCH / 32, UDIM / 64), 256, 0, stream>>>(
        (const short8*)hcH, (const short8*)hcL,
        (const short8*)w2Hi, (const short8*)w2Lo,
        W2_b, tmp2, UDIM / 32, UDIM);

    // ---- greedy decode: 24 steps x 3 dispatches ----
    for (int st = 0; st < TDEC - 1; st++) {
        attn_ctx<<<BATCH, 1024, 0, stream>>>(
            encProjF, encAHi, encALo, tmp2, V_W, V_b, o2hT, idx, gxHi, gxLo);
        dec_gru3<<<dim3(64, 4), 768, 0, stream>>>(
            (const short8*)hcH, (const short8*)hcL,
            (const short8*)gxHi, (const short8*)gxLo,
            (const short8*)dWrH, (const short8*)dWrL,
            (const short8*)dWzH, (const short8*)dWzL,
            (const short8*)dWnhH, (const short8*)dWnhL,
            (const short8*)dWniH, (const short8*)dWniL,
            dec_bih, dec_bhh, hcF, hnF, hnH, hnL);
        float* pred = out + (size_t)(1 + st) * BATCH * VOUTD;
        int nblk = (st == TDEC - 2) ? 16 : 144;   // last step: tmp2 dead
        fcw2<<<nblk, 256, 0, stream>>>(
            (const short8*)hnH, (const short8*)hnL,
            (const short8*)fcHi, (const short8*)fcLo,
            fc_b, pred, idx,
            (const short8*)w2Hi, (const short8*)w2Lo, W2_b, tmp2);
        { float* tf = hcF; hcF = hnF; hnF = tf; }
        { short* th = hcH; hcH = hnH; hnH = th; th = hcL; hcL = hnL; hnL = th; }
    }
}

// Round 10
// 3347.469 us; speedup vs baseline: 1.0531x; 1.0284x over previous
//
#include <hip/hip_runtime.h>
#include <math.h>

#define SLEN 64
#define BATCH 256
#define VIND 128
#define VOUTD 128
#define UDIM 1024
#define EDIM 512
#define TDEC 25
#define GXW 1536
#define U3 3072
#define NSEG 12

typedef __attribute__((ext_vector_type(8))) short short8;
typedef __attribute__((ext_vector_type(4))) float f32x4;

#define MFMA(acc, A, B) acc = __builtin_amdgcn_mfma_f32_16x16x32_bf16((A), (B), (acc), 0, 0, 0)

// libm sigmoid/tanh in the RECURRENT path (gates): fast variants drift over the
// 64-step encoder + 24-step decoder recurrence and flip greedy argmax (R1 fail).
__device__ __forceinline__ float sigm(float x) { return 1.f / (1.f + expf(-x)); }

// fast tanh for the attention SCORE path only (non-recurrent-critical)
__device__ __forceinline__ float tanhf_fast(float x) {
    float ax = fabsf(x);
    float e = __expf(-2.f * ax);
    float t = (1.f - e) / (1.f + e);
    return copysignf(t, x);
}

__device__ __forceinline__ short f2bf(float f) {
    unsigned u = __float_as_uint(f);
    u += 0x7FFF + ((u >> 16) & 1);
    return (short)(u >> 16);
}
__device__ __forceinline__ float bf2f(short h) {
    return __uint_as_float(((unsigned)(unsigned short)h) << 16);
}

// fragment-major packed layout for operand X[R][K]:
// chunk(r,k) holds X[r][k..k+8); lane = (r&15) + 16*((k>>3)&3)
__device__ __forceinline__ size_t pkChunk(int r, int k, int K) {
    return ((size_t)(r >> 4) * (K >> 5) + (k >> 5)) * 64 + ((r & 15) + 16 * ((k >> 3) & 3));
}

union S8 { short s[8]; short8 v; };

__device__ __forceinline__ void writeSplit8(short* Hi, short* Lo, size_t chunk,
                                            const float* vals) {
    S8 h, l;
#pragma unroll
    for (int j = 0; j < 8; j++) {
        short hb = f2bf(vals[j]);
        h.s[j] = hb;
        l.s[j] = f2bf(vals[j] - bf2f(hb));
    }
    ((short8*)Hi)[chunk] = h.v;
    ((short8*)Lo)[chunk] = l.v;
}

// ---------------------------------------------------------------------------
__global__ void init_kernel(float* __restrict__ h0, short* __restrict__ hpHi,
                            short* __restrict__ hpLo, float* __restrict__ out0,
                            int* __restrict__ idx,
                            const float* __restrict__ o2h_W,
                            const float* __restrict__ o2h_b,
                            float* __restrict__ o2hT) {
    int i = blockIdx.x * 256 + threadIdx.x;
    if (i < BATCH * UDIM) { h0[i] = 0.f; hpHi[i] = 0; hpLo[i] = 0; }
    if (i < BATCH * VOUTD) out0[i] = ((i & (VOUTD - 1)) == 0) ? 1.f : 0.f;
    if (i < BATCH) idx[i] = 0;
    if (i < VOUTD * EDIM) {
        // o2hT[v][e] = o2h_W[e][v] + o2h_b[e]  (bias folded, row-read at decode)
        int v = i >> 9, e = i & (EDIM - 1);
        o2hT[i] = o2h_W[(size_t)e * VOUTD + v] + o2h_b[e];
    }
}

// ---------------------------------------------------------------------------
// All weight/input packing in ONE kernel: segment table passed by value.
// ---------------------------------------------------------------------------
struct PackSeg {
    const float* sA; const float* sB;
    short* Hi; short* Lo;
    int KA, KB, offA, offB, chunkStart;
};
struct PackArgs { PackSeg s[NSEG]; };

__global__ void pack_all(PackArgs pa, int total) {
    int gid = blockIdx.x * 256 + threadIdx.x;
    if (gid >= total) return;
    int si = 0;
#pragma unroll
    for (int i = 1; i < NSEG; i++) si = (gid >= pa.s[i].chunkStart) ? i : si;
    PackSeg sg = pa.s[si];
    int local = gid - sg.chunkStart;
    int K = sg.KA + sg.KB;
    int cpr = K >> 3;
    int r = local / cpr, k0 = (local - r * cpr) * 8;
    const float* src = (k0 < sg.KA)
        ? sg.sA + (size_t)(sg.offA + r) * sg.KA + k0
        : sg.sB + (size_t)(sg.offB + r) * sg.KB + (k0 - sg.KA);
    float v[8];
#pragma unroll
    for (int j = 0; j < 8; j++) v[j] = src[j];
    writeSplit8(sg.Hi, sg.Lo, pkChunk(r, k0, K), v);
}

// ---------------------------------------------------------------------------
// Split-bf16 3-pass MFMA GEMM, BM=64 x BN=128 block (4 waves of 32x64).
// ---------------------------------------------------------------------------
__global__ __launch_bounds__(256) void gemm_w(
    const short8* __restrict__ Ahi, const short8* __restrict__ Alo,
    const short8* __restrict__ Whi, const short8* __restrict__ Wlo,
    const float* __restrict__ bias, float* __restrict__ C,
    int KT, int N) {
    int tid = threadIdx.x, lane = tid & 63, wave = tid >> 6;
    int m16 = blockIdx.x * 4 + (wave & 1) * 2;
    int nb = blockIdx.y * 8 + (wave >> 1) * 4;
    const short8* a0h = Ahi + (size_t)m16 * KT * 64 + lane;
    const short8* a1h = a0h + (size_t)KT * 64;
    const short8* a0l = Alo + (size_t)m16 * KT * 64 + lane;
    const short8* a1l = a0l + (size_t)KT * 64;
    const short8* w0h = Whi + (size_t)(nb + 0) * KT * 64 + lane;
    const short8* w1h = Whi + (size_t)(nb + 1) * KT * 64 + lane;
    const short8* w2h = Whi + (size_t)(nb + 2) * KT * 64 + lane;
    const short8* w3h = Whi + (size_t)(nb + 3) * KT * 64 + lane;
    const short8* w0l = Wlo + (size_t)(nb + 0) * KT * 64 + lane;
    const short8* w1l = Wlo + (size_t)(nb + 1) * KT * 64 + lane;
    const short8* w2l = Wlo + (size_t)(nb + 2) * KT * 64 + lane;
    const short8* w3l = Wlo + (size_t)(nb + 3) * KT * 64 + lane;
    f32x4 acc0[4] = {}, acc1[4] = {};

    for (int kt = 0; kt < KT; kt++) {
        size_t o = (size_t)kt * 64;
        short8 A0H = a0h[o], A1H = a1h[o], A0L = a0l[o], A1L = a1l[o];
        short8 WH0 = w0h[o], WL0 = w0l[o];
        MFMA(acc0[0], A0H, WH0); MFMA(acc1[0], A1H, WH0);
        MFMA(acc0[0], A0H, WL0); MFMA(acc1[0], A1H, WL0);
        MFMA(acc0[0], A0L, WH0); MFMA(acc1[0], A1L, WH0);
        short8 WH1 = w1h[o], WL1 = w1l[o];
        MFMA(acc0[1], A0H, WH1); MFMA(acc1[1], A1H, WH1);
        MFMA(acc0[1], A0H, WL1); MFMA(acc1[1], A1H, WL1);
        MFMA(acc0[1], A0L, WH1); MFMA(acc1[1], A1L, WH1);
        short8 WH2 = w2h[o], WL2 = w2l[o];
        MFMA(acc0[2], A0H, WH2); MFMA(acc1[2], A1H, WH2);
        MFMA(acc0[2], A0H, WL2); MFMA(acc1[2], A1H, WL2);
        MFMA(acc0[2], A0L, WH2); MFMA(acc1[2], A1L, WH2);
        short8 WH3 = w3h[o], WL3 = w3l[o];
        MFMA(acc0[3], A0H, WH3); MFMA(acc1[3], A1H, WH3);
        MFMA(acc0[3], A0H, WL3); MFMA(acc1[3], A1H, WL3);
        MFMA(acc0[3], A0L, WH3); MFMA(acc1[3], A1L, WH3);
    }
    int rsub = (lane >> 4) * 4, cn = lane & 15;
    int row0 = (m16 + 0) * 16 + rsub;
    int row1 = (m16 + 1) * 16 + rsub;
#pragma unroll
    for (int j = 0; j < 4; j++) {
        int col = (nb + j) * 16 + cn;
        float bb = bias ? bias[col] : 0.f;
#pragma unroll
        for (int r = 0; r < 4; r++) {
            C[(size_t)(row0 + r) * N + col] = acc0[j][r] + bb;
            C[(size_t)(row1 + r) * N + col] = acc1[j][r] + bb;
        }
    }
}

// ---------------------------------------------------------------------------
// BM=32 GEMM for the pre-loop tmp2. Grid (M/32, N/64).
// ---------------------------------------------------------------------------
__global__ __launch_bounds__(256) void gemm_bm32(
    const short8* __restrict__ Ahi, const short8* __restrict__ Alo,
    const short8* __restrict__ Whi, const short8* __restrict__ Wlo,
    const float* __restrict__ bias, float* __restrict__ C,
    int KT, int N) {
    int tid = threadIdx.x, lane = tid & 63, wave = tid >> 6;
    int m16 = blockIdx.x * 2 + (wave & 1);
    int n16 = blockIdx.y * 4 + (wave >> 1) * 2;
    const short8* ah = Ahi + (size_t)m16 * KT * 64 + lane;
    const short8* al = Alo + (size_t)m16 * KT * 64 + lane;
    const short8* w0h = Whi + (size_t)n16 * KT * 64 + lane;
    const short8* w1h = w0h + (size_t)KT * 64;
    const short8* w0l = Wlo + (size_t)n16 * KT * 64 + lane;
    const short8* w1l = w0l + (size_t)KT * 64;
    f32x4 a0 = {0,0,0,0}, a1 = {0,0,0,0};
    for (int kt = 0; kt < KT; kt++) {
        size_t o = (size_t)kt * 64;
        short8 AH = ah[o], AL = al[o];
        short8 W0H = w0h[o], W0L = w0l[o], W1H = w1h[o], W1L = w1l[o];
        MFMA(a0, AH, W0H); MFMA(a1, AH, W1H);
        MFMA(a0, AH, W0L); MFMA(a1, AH, W1L);
        MFMA(a0, AL, W0H); MFMA(a1, AL, W1H);
    }
    int rsub = (lane >> 4) * 4, cn = lane & 15;
    float b0 = bias ? bias[(n16 + 0) * 16 + cn] : 0.f;
    float b1 = bias ? bias[(n16 + 1) * 16 + cn] : 0.f;
#pragma unroll
    for (int r = 0; r < 4; r++) {
        int row = m16 * 16 + rsub + r;
        C[(size_t)row * N + (n16 + 0) * 16 + cn] = a0[r] + b0;
        C[(size_t)row * N + (n16 + 1) * 16 + cn] = a1[r] + b1;
    }
}

// ---------------------------------------------------------------------------
// Encoder GRU step with FUSED gi: 12 waves = (gate x K-half x m-pair), each
// wave covers two m16 tiles. The x@Wih^T part (K=128, 2 kt per K-half) is
// accumulated directly: r/z gates into the same MFMA chain as the h-part
// (exact-arithmetic identical; fp-reorder class), n gate into a separate
// accumulator (reference multiplies only the h-part by r). Eliminates the
// gi producer GEMMs + 400 MB of gi write/read traffic. Grid (64, 4).
// ---------------------------------------------------------------------------
__global__ __launch_bounds__(768) void enc_gru3(
    const short8* __restrict__ hinH8, const short8* __restrict__ hinL8,
    const short8* __restrict__ xH8, const short8* __restrict__ xL8,
    const short8* __restrict__ WihH, const short8* __restrict__ WihL,
    const short8* __restrict__ WrH, const short8* __restrict__ WrL,
    const short8* __restrict__ WzH, const short8* __restrict__ WzL,
    const short8* __restrict__ WnH, const short8* __restrict__ WnL,
    const float* __restrict__ bih, const float* __restrict__ bhh,
    const float* __restrict__ hinF, float* __restrict__ houtF,
    short* __restrict__ hoH, short* __restrict__ hoL,
    short* __restrict__ eaHi, short* __restrict__ eaLo,
    const int* __restrict__ x_len, int t) {
    __shared__ float sC[8][4][16][16];   // r:0,1 z:2,3 nh:4,5 ni:6,7
    __shared__ float sHo[4][16][16];
    __shared__ float sEo[4][16][16];
    int tid = threadIdx.x, lane = tid & 63, wave = tid >> 6;  // wave 0..11
    int g = blockIdx.x;
    int m16a = blockIdx.y * 4;
    int gate = wave >> 2, hm = wave & 3, half = hm >> 1, mp = hm & 1;
    int t0 = mp * 2;  // this wave's tiles: t0, t0+1
    // ---- h-part operands (K=1024, 16 kt per half) ----
    const short8* a0h = hinH8 + (size_t)(m16a + t0) * 32 * 64 + (size_t)half * 16 * 64 + lane;
    const short8* a0l = hinL8 + (size_t)(m16a + t0) * 32 * 64 + (size_t)half * 16 * 64 + lane;
    const short8* a1h = a0h + (size_t)32 * 64;
    const short8* a1l = a0l + (size_t)32 * 64;
    const short8* WH0 = (gate == 0) ? WrH : (gate == 1) ? WzH : WnH;
    const short8* WL0 = (gate == 0) ? WrL : (gate == 1) ? WzL : WnL;
    const short8* wh = WH0 + (size_t)g * 32 * 64 + (size_t)half * 16 * 64 + lane;
    const short8* wl = WL0 + (size_t)g * 32 * 64 + (size_t)half * 16 * 64 + lane;
    // ---- x-part operands (K=128, 2 kt per half); x tile = t*16 + m16 ----
    const short8* x0h = xH8 + ((size_t)(t * 16 + m16a + t0) * 4 + half * 2) * 64 + lane;
    const short8* x0l = xL8 + ((size_t)(t * 16 + m16a + t0) * 4 + half * 2) * 64 + lane;
    const short8* x1h = x0h + (size_t)4 * 64;
    const short8* x1l = x0l + (size_t)4 * 64;
    const short8* wxh = WihH + ((size_t)(gate * 64 + g) * 4 + half * 2) * 64 + lane;
    const short8* wxl = WihL + ((size_t)(gate * 64 + g) * 4 + half * 2) * 64 + lane;

    f32x4 accA0 = {0, 0, 0, 0}, accA1 = {0, 0, 0, 0};
    for (int kt = 0; kt < 16; kt++) {
        size_t o = (size_t)kt * 64;
        short8 WH = wh[o], WL = wl[o];
        short8 A0H = a0h[o], A0L = a0l[o];
        MFMA(accA0, A0H, WH); MFMA(accA0, A0H, WL); MFMA(accA0, A0L, WH);
        short8 A1H = a1h[o], A1L = a1l[o];
        MFMA(accA1, A1H, WH); MFMA(accA1, A1H, WL); MFMA(accA1, A1L, WH);
    }
    f32x4 accX0 = {0, 0, 0, 0}, accX1 = {0, 0, 0, 0};
    if (gate < 2) {
        // r/z: x-part joins the same accumulator chain (exact-arith identical)
#pragma unroll
        for (int kt = 0; kt < 2; kt++) {
            size_t o = (size_t)kt * 64;
            short8 WH = wxh[o], WL = wxl[o];
            short8 X0H = x0h[o], X0L = x0l[o];
            MFMA(accA0, X0H, WH); MFMA(accA0, X0H, WL); MFMA(accA0, X0L, WH);
            short8 X1H = x1h[o], X1L = x1l[o];
            MFMA(accA1, X1H, WH); MFMA(accA1, X1H, WL); MFMA(accA1, X1L, WH);
        }
    } else {
        // n: x-part (ni) kept separate from h-part (nh)
#pragma unroll
        for (int kt = 0; kt < 2; kt++) {
            size_t o = (size_t)kt * 64;
            short8 WH = wxh[o], WL = wxl[o];
            short8 X0H = x0h[o], X0L = x0l[o];
            MFMA(accX0, X0H, WH); MFMA(accX0, X0H, WL); MFMA(accX0, X0L, WH);
            short8 X1H = x1h[o], X1L = x1l[o];
            MFMA(accX1, X1H, WH); MFMA(accX1, X1H, WL); MFMA(accX1, X1L, WH);
        }
    }
    {
        int rsub = (lane >> 4) << 2, cn = lane & 15;
        if (gate < 2) {
            int slot = gate * 2 + half;
#pragma unroll
            for (int j = 0; j < 4; j++) {
                sC[slot][t0 + 0][rsub + j][cn] = accA0[j];
                sC[slot][t0 + 1][rsub + j][cn] = accA1[j];
            }
        } else {
#pragma unroll
            for (int j = 0; j < 4; j++) {
                sC[4 + half][t0 + 0][rsub + j][cn] = accA0[j];  // nh
                sC[4 + half][t0 + 1][rsub + j][cn] = accA1[j];
                sC[6 + half][t0 + 0][rsub + j][cn] = accX0[j];  // ni
                sC[6 + half][t0 + 1][rsub + j][cn] = accX1[j];
            }
        }
    }
    __syncthreads();
    if (wave < 4) {
        int tile = wave;
        int m16 = m16a + tile;
        int cu = g * 16 + (lane & 15);
        int rsub = (lane >> 4) << 2;
        float b_r = bih[cu] + bhh[cu];
        float b_z = bih[UDIM + cu] + bhh[UDIM + cu];
        float b_nh = bhh[2 * UDIM + cu];
        float b_ni = bih[2 * UDIM + cu];
#pragma unroll
        for (int j = 0; j < 4; j++) {
            int rr = rsub + j, cc = lane & 15;
            int b = m16 * 16 + rr;
            float rS = sC[0][tile][rr][cc] + sC[1][tile][rr][cc];
            float zS = sC[2][tile][rr][cc] + sC[3][tile][rr][cc];
            float nhS = sC[4][tile][rr][cc] + sC[5][tile][rr][cc];
            float niS = sC[6][tile][rr][cc] + sC[7][tile][rr][cc];
            float rg = sigm(rS + b_r);
            float zg = sigm(zS + b_z);
            float nn = tanhf(niS + b_ni + rg * (nhS + b_nh));
            float hp = hinF[(size_t)b * UDIM + cu];
            float hv = (1.f - zg) * nn + zg * hp;
            bool msk = t < x_len[b];
            float ho = msk ? hv : hp;
            houtF[(size_t)b * UDIM + cu] = ho;
            sHo[tile][rr][cc] = ho;
            sEo[tile][rr][cc] = msk ? hv : 0.f;
        }
    }
    __syncthreads();
    if (wave >= 4 && wave < 8 && lane < 32) {
        int tile = wave - 4;
        int m16 = m16a + tile;
        int rr = lane >> 1, oct = lane & 1;
        int brow = m16 * 16 + rr;
        int u0 = g * 16 + oct * 8;
        float v[8];
#pragma unroll
        for (int j = 0; j < 8; j++) v[j] = sHo[tile][rr][oct * 8 + j];
        writeSplit8(hoH, hoL, pkChunk(brow, u0, UDIM), v);
#pragma unroll
        for (int j = 0; j < 8; j++) v[j] = sEo[tile][rr][oct * 8 + j];
        writeSplit8(eaHi, eaLo, pkChunk(brow * SLEN + t, u0, UDIM), v);
    }
}

// ---------------------------------------------------------------------------
// Decoder GRU step: 12 waves = (gate x K-half x m-pair); block covers FOUR
// m16 tiles (R6 structure — best known). Grid (64, 4).
// ---------------------------------------------------------------------------
__global__ __launch_bounds__(768) void dec_gru3(
    const short8* __restrict__ hinH8, const short8* __restrict__ hinL8,
    const short8* __restrict__ gxH8, const short8* __restrict__ gxL8,
    const short8* __restrict__ WrH, const short8* __restrict__ WrL,
    const short8* __restrict__ WzH, const short8* __restrict__ WzL,
    const short8* __restrict__ WnhH, const short8* __restrict__ WnhL,
    const short8* __restrict__ WniH, const short8* __restrict__ WniL,
    const float* __restrict__ bih, const float* __restrict__ bhh,
    const float* __restrict__ hinF, float* __restrict__ houtF,
    short* __restrict__ hoH, short* __restrict__ hoL) {
    __shared__ float sC[8][4][16][16];
    __shared__ float sHo[4][16][16];
    int tid = threadIdx.x, lane = tid & 63, wave = tid >> 6;  // 0..11
    int g = blockIdx.x;
    int m16a = blockIdx.y * 4;
    int gate = wave >> 2, hm = wave & 3, half = hm >> 1, mp = hm & 1;
    int t0 = mp * 2;
    const short8* a0h = hinH8 + (size_t)(m16a + t0) * 32 * 64 + (size_t)half * 16 * 64 + lane;
    const short8* a0l = hinL8 + (size_t)(m16a + t0) * 32 * 64 + (size_t)half * 16 * 64 + lane;
    const short8* a1h = a0h + (size_t)32 * 64;
    const short8* a1l = a0l + (size_t)32 * 64;
    const short8* g0h = gxH8 + (size_t)(m16a + t0) * 48 * 64 + (size_t)half * 24 * 64 + lane;
    const short8* g0l = gxL8 + (size_t)(m16a + t0) * 48 * 64 + (size_t)half * 24 * 64 + lane;
    const short8* g1h = g0h + (size_t)48 * 64;
    const short8* g1l = g0l + (size_t)48 * 64;
    const short8 *whA, *wlA, *whB, *wlB;
    if (gate == 0) {
        whA = WrH + (size_t)g * 80 * 64 + (size_t)half * 16 * 64 + lane;
        wlA = WrL + (size_t)g * 80 * 64 + (size_t)half * 16 * 64 + lane;
        whB = WrH + (size_t)g * 80 * 64 + (size_t)(32 + half * 24) * 64 + lane;
        wlB = WrL + (size_t)g * 80 * 64 + (size_t)(32 + half * 24) * 64 + lane;
    } else if (gate == 1) {
        whA = WzH + (size_t)g * 80 * 64 + (size_t)half * 16 * 64 + lane;
        wlA = WzL + (size_t)g * 80 * 64 + (size_t)half * 16 * 64 + lane;
        whB = WzH + (size_t)g * 80 * 64 + (size_t)(32 + half * 24) * 64 + lane;
        wlB = WzL + (size_t)g * 80 * 64 + (size_t)(32 + half * 24) * 64 + lane;
    } else {
        whA = WnhH + (size_t)g * 32 * 64 + (size_t)half * 16 * 64 + lane;
        wlA = WnhL + (size_t)g * 32 * 64 + (size_t)half * 16 * 64 + lane;
        whB = WniH + (size_t)g * 48 * 64 + (size_t)half * 24 * 64 + lane;
        wlB = WniL + (size_t)g * 48 * 64 + (size_t)half * 24 * 64 + lane;
    }
    f32x4 accA0 = {0,0,0,0}, accA1 = {0,0,0,0};
    f32x4 accB0 = {0,0,0,0}, accB1 = {0,0,0,0};
    for (int kt = 0; kt < 16; kt++) {
        size_t o = (size_t)kt * 64;
        short8 WH = whA[o], WL = wlA[o];
        short8 A0H = a0h[o], A0L = a0l[o];
        MFMA(accA0, A0H, WH); MFMA(accA0, A0H, WL); MFMA(accA0, A0L, WH);
        short8 A1H = a1h[o], A1L = a1l[o];
        MFMA(accA1, A1H, WH); MFMA(accA1, A1H, WL); MFMA(accA1, A1L, WH);
    }
    for (int kt = 0; kt < 24; kt++) {
        size_t o = (size_t)kt * 64;
        short8 WH = whB[o], WL = wlB[o];
        short8 G0H = g0h[o], G0L = g0l[o];
        MFMA(accB0, G0H, WH); MFMA(accB0, G0H, WL); MFMA(accB0, G0L, WH);
        short8 G1H = g1h[o], G1L = g1l[o];
        MFMA(accB1, G1H, WH); MFMA(accB1, G1H, WL); MFMA(accB1, G1L, WH);
    }
    {
        int rsub = (lane >> 4) << 2, cn = lane & 15;
        if (gate < 2) {
            int slot = gate * 2 + half;
#pragma unroll
            for (int j = 0; j < 4; j++) {
                sC[slot][t0 + 0][rsub + j][cn] = accA0[j] + accB0[j];
                sC[slot][t0 + 1][rsub + j][cn] = accA1[j] + accB1[j];
            }
        } else {
#pragma unroll
            for (int j = 0; j < 4; j++) {
                sC[4 + half][t0 + 0][rsub + j][cn] = accA0[j];  // nh
                sC[4 + half][t0 + 1][rsub + j][cn] = accA1[j];
                sC[6 + half][t0 + 0][rsub + j][cn] = accB0[j];  // ni
                sC[6 + half][t0 + 1][rsub + j][cn] = accB1[j];
            }
        }
    }
    __syncthreads();
    if (wave < 4) {
        int tile = wave;
        int m16 = m16a + tile;
        int cu = g * 16 + (lane & 15);
        int rsub = (lane >> 4) << 2;
        float b_r = bih[cu] + bhh[cu];
        float b_z = bih[UDIM + cu] + bhh[UDIM + cu];
        float b_nh = bhh[2 * UDIM + cu];
        float b_ni = bih[2 * UDIM + cu];
#pragma unroll
        for (int j = 0; j < 4; j++) {
            int rr = rsub + j, cc = lane & 15;
            int b = m16 * 16 + rr;
            float rg = sigm(sC[0][tile][rr][cc] + sC[1][tile][rr][cc] + b_r);
            float zg = sigm(sC[2][tile][rr][cc] + sC[3][tile][rr][cc] + b_z);
            float nn = tanhf(sC[6][tile][rr][cc] + sC[7][tile][rr][cc] + b_ni +
                             rg * (sC[4][tile][rr][cc] + sC[5][tile][rr][cc] + b_nh));
            float hp = hinF[(size_t)b * UDIM + cu];
            float hv = (1.f - zg) * nn + zg * hp;
            houtF[(size_t)b * UDIM + cu] = hv;
            sHo[tile][rr][cc] = hv;
        }
    }
    __syncthreads();
    if (wave >= 4 && wave < 8 && lane < 32) {
        int tile = wave - 4;
        int m16 = m16a + tile;
        int rr = lane >> 1, oct = lane & 1;
        int brow = m16 * 16 + rr;
        int u0 = g * 16 + oct * 8;
        float v[8];
#pragma unroll
        for (int j = 0; j < 8; j++) v[j] = sHo[tile][rr][oct * 8 + j];
        writeSplit8(hoH, hoL, pkChunk(brow, u0, UDIM), v);
    }
}

// ---------------------------------------------------------------------------
// Attention + ctx + emb -> gx split-pack. 1024-thread blocks (16 waves/CU):
// score pass 16-wave s-stride; ctx pass 8-way s-split with LDS combine;
// emb reads pre-transposed bias-folded o2hT row (coalesced).
// ---------------------------------------------------------------------------
__global__ __launch_bounds__(1024) void attn_ctx(
    const float* __restrict__ encProj,
    const short* __restrict__ eaHi, const short* __restrict__ eaLo,
    const float* __restrict__ tmp2, const float* __restrict__ V_W,
    const float* __restrict__ V_b,
    const float* __restrict__ o2hT,
    const int* __restrict__ idx, short* __restrict__ gxHi, short* __restrict__ gxLo) {
    int b = blockIdx.x;
    int tid = threadIdx.x, lane = tid & 63, wave = tid >> 6;
    __shared__ float s_t2[UDIM];
    __shared__ float s_v[UDIM];
    __shared__ float s_attn[SLEN];
    __shared__ float s_part[7][128][9];  // pad 9 floats: conflict-free combine
    for (int u = tid; u < UDIM; u += 1024) {
        s_t2[u] = tmp2[(size_t)b * UDIM + u];
        s_v[u] = V_W[u];
    }
    __syncthreads();
    for (int s = wave; s < SLEN; s += 16) {
        const float4* ep4 = (const float4*)(encProj + ((size_t)b * SLEN + s) * UDIM);
        float p = 0.f;
        for (int u4 = lane; u4 < UDIM / 4; u4 += 64) {
            float4 e = ep4[u4];
            int u = 4 * u4;
            p += tanhf_fast(e.x + s_t2[u]) * s_v[u] +
                 tanhf_fast(e.y + s_t2[u + 1]) * s_v[u + 1] +
                 tanhf_fast(e.z + s_t2[u + 2]) * s_v[u + 2] +
                 tanhf_fast(e.w + s_t2[u + 3]) * s_v[u + 3];
        }
#pragma unroll
        for (int off = 32; off > 0; off >>= 1) p += __shfl_xor(p, off);
        if (lane == 0) s_attn[s] = p + V_b[0];
    }
    __syncthreads();
    if (tid < 64) {
        float v = s_attn[tid];
        float mx = v;
#pragma unroll
        for (int off = 32; off > 0; off >>= 1) mx = fmaxf(mx, __shfl_xor(mx, off));
        float e = expf(v - mx);
        float sum = e;
#pragma unroll
        for (int off = 32; off > 0; off >>= 1) sum += __shfl_xor(sum, off);
        s_attn[tid] = e / sum;
    }
    __syncthreads();
    {
        int grp = tid >> 7, tu = tid & 127;  // 8 s-groups x 128 u-threads
        int u0 = tu * 8;
        float a[8] = {0, 0, 0, 0, 0, 0, 0, 0};
        const short8* hi8 = (const short8*)eaHi;
        const short8* lo8 = (const short8*)eaLo;
        int lanePart = 16 * ((u0 >> 3) & 3);
        int colPart = u0 >> 5;
        for (int s = grp * 8; s < grp * 8 + 8; s++) {
            int r = b * SLEN + s;
            size_t ch = ((size_t)(r >> 4) * (UDIM >> 5) + colPart) * 64 + (r & 15) + lanePart;
            S8 h, l;
            h.v = hi8[ch];
            l.v = lo8[ch];
            float w = s_attn[s];
#pragma unroll
            for (int j = 0; j < 8; j++) a[j] += w * (bf2f(h.s[j]) + bf2f(l.s[j]));
        }
        if (grp) {
#pragma unroll
            for (int j = 0; j < 8; j++) s_part[grp - 1][tu][j] = a[j];
        }
        __syncthreads();
        if (tid < 128) {
#pragma unroll
            for (int gg = 0; gg < 7; gg++)
#pragma unroll
                for (int j = 0; j < 8; j++) a[j] += s_part[gg][tu][j];
            writeSplit8(gxHi, gxLo, pkChunk(b, u0, GXW), a);
        } else if (tid < 192) {
            int e0 = (tid - 128) * 8;
            int ib = idx[b];
            const float* row = o2hT + (size_t)ib * EDIM + e0;
            float v[8];
#pragma unroll
            for (int j = 0; j < 8; j++) v[j] = row[j];
            writeSplit8(gxHi, gxLo, pkChunk(b, UDIM + e0, GXW), v);
        }
    }
}

// ---------------------------------------------------------------------------
// Merged: pred=h@fc^T+b + parallel first-max argmax (blocks 0..15) AND
// tmp2=h@W2^T+b for the next step (blocks 16..143). Final decode step
// launches only 16 blocks (tmp2 dead).
// ---------------------------------------------------------------------------
__global__ __launch_bounds__(256) void fcw2(
    const short8* __restrict__ hHi, const short8* __restrict__ hLo,
    const short8* __restrict__ fcH, const short8* __restrict__ fcL,
    const float* __restrict__ fc_b, float* __restrict__ pred,
    int* __restrict__ idx,
    const short8* __restrict__ w2H, const short8* __restrict__ w2L,
    const float* __restrict__ W2_b, float* __restrict__ tmp2) {
    __shared__ float sP[16][129];
    int tid = threadIdx.x, lane = tid & 63, wave = tid >> 6;
    if (blockIdx.x < 16) {
        int fm = blockIdx.x;
        const short8* ah = hHi + (size_t)fm * 32 * 64 + lane;
        const short8* al = hLo + (size_t)fm * 32 * 64 + lane;
        int n0 = 2 * wave, n1 = 2 * wave + 1;
        const short8* w0h = fcH + (size_t)n0 * 32 * 64 + lane;
        const short8* w0l = fcL + (size_t)n0 * 32 * 64 + lane;
        const short8* w1h = fcH + (size_t)n1 * 32 * 64 + lane;
        const short8* w1l = fcL + (size_t)n1 * 32 * 64 + lane;
        f32x4 a0 = {0,0,0,0}, a1 = {0,0,0,0};
        for (int kt = 0; kt < 32; kt++) {
            size_t o = (size_t)kt * 64;
            short8 AH = ah[o], AL = al[o];
            short8 W0H = w0h[o], W0L = w0l[o], W1H = w1h[o], W1L = w1l[o];
            MFMA(a0, AH, W0H); MFMA(a1, AH, W1H);
            MFMA(a0, AH, W0L); MFMA(a1, AH, W1L);
            MFMA(a0, AL, W0H); MFMA(a1, AL, W1H);
        }
        int cn = lane & 15, rsub = (lane >> 4) << 2;
#pragma unroll
        for (int j = 0; j < 4; j++) {
            sP[rsub + j][n0 * 16 + cn] = a0[j] + fc_b[n0 * 16 + cn];
            sP[rsub + j][n1 * 16 + cn] = a1[j] + fc_b[n1 * 16 + cn];
        }
        __syncthreads();
        {
            int row = tid >> 4, c0 = (tid & 15) * 8;
            float* pr = pred + (size_t)(fm * 16 + row) * VOUTD;
#pragma unroll
            for (int j = 0; j < 8; j++) pr[c0 + j] = sP[row][c0 + j];
        }
        if (tid < 128) {
            // 8 lanes per row, first-max semantics (strict > in scan order,
            // smaller index wins ties across segments)
            int row = tid >> 3, seg = tid & 7;
            float v = -1e30f;
            int bi = 0;
            int c0 = seg * 16;
            for (int j = c0; j < c0 + 16; j++) {
                float w = sP[row][j];
                if (w > v) { v = w; bi = j; }
            }
#pragma unroll
            for (int off = 1; off < 8; off <<= 1) {
                float ov = __shfl_xor(v, off);
                int obi = __shfl_xor(bi, off);
                if (ov > v || (ov == v && obi < bi)) { v = ov; bi = obi; }
            }
            if (seg == 0) idx[fm * 16 + row] = bi;
        }
    } else {
        int lin = blockIdx.x - 16;       // 0..127
        int bx = lin & 7, by = lin >> 3; // bm32 grid (8, 16)
        int m16 = bx * 2 + (wave & 1);
        int n16 = by * 4 + (wave >> 1) * 2;
        const short8* ah = hHi + (size_t)m16 * 32 * 64 + lane;
        const short8* al = hLo + (size_t)m16 * 32 * 64 + lane;
        const short8* w0h = w2H + (size_t)n16 * 32 * 64 + lane;
        const short8* w1h = w0h + (size_t)32 * 64;
        const short8* w0l = w2L + (size_t)n16 * 32 * 64 + lane;
        const short8* w1l = w0l + (size_t)32 * 64;
        f32x4 a0 = {0,0,0,0}, a1 = {0,0,0,0};
        for (int kt = 0; kt < 32; kt++) {
            size_t o = (size_t)kt * 64;
            short8 AH = ah[o], AL = al[o];
            short8 W0H = w0h[o], W0L = w0l[o], W1H = w1h[o], W1L = w1l[o];
            MFMA(a0, AH, W0H); MFMA(a1, AH, W1H);
            MFMA(a0, AH, W0L); MFMA(a1, AH, W1L);
            MFMA(a0, AL, W0H); MFMA(a1, AL, W1H);
        }
        int rsub = (lane >> 4) * 4, cn = lane & 15;
        float b0 = W2_b[(n16 + 0) * 16 + cn];
        float b1 = W2_b[(n16 + 1) * 16 + cn];
#pragma unroll
        for (int r = 0; r < 4; r++) {
            int row = m16 * 16 + rsub + r;
            tmp2[(size_t)row * UDIM + (n16 + 0) * 16 + cn] = a0[r] + b0;
            tmp2[(size_t)row * UDIM + (n16 + 1) * 16 + cn] = a1[r] + b1;
        }
    }
}

// ---------------------------------------------------------------------------
extern "C" void kernel_launch(void* const* d_in, const int* in_sizes, int n_in,
                              void* d_out, int out_size, void* d_ws, size_t ws_size,
                              hipStream_t stream) {
    const float* x       = (const float*)d_in[0];
    const int*   x_len   = (const int*)d_in[1];
    const float* enc_Wih = (const float*)d_in[2];
    const float* enc_Whh = (const float*)d_in[3];
    const float* enc_bih = (const float*)d_in[4];
    const float* enc_bhh = (const float*)d_in[5];
    const float* dec_Wih = (const float*)d_in[6];
    const float* dec_Whh = (const float*)d_in[7];
    const float* dec_bih = (const float*)d_in[8];
    const float* dec_bhh = (const float*)d_in[9];
    const float* o2h_W   = (const float*)d_in[10];
    const float* o2h_b   = (const float*)d_in[11];
    const float* fc_W    = (const float*)d_in[12];
    const float* fc_b    = (const float*)d_in[13];
    const float* W1_W    = (const float*)d_in[14];
    const float* W1_b    = (const float*)d_in[15];
    const float* W2_W    = (const float*)d_in[16];
    const float* W2_b    = (const float*)d_in[17];
    const float* V_W     = (const float*)d_in[18];
    const float* V_b     = (const float*)d_in[19];
    float* out = (float*)d_out;

    char* p = (char*)d_ws;
    auto alloc = [&](size_t bytes) -> char* {
        char* q = p;
        p += (bytes + 255) & ~(size_t)255;
        return q;
    };
    float* hAF  = (float*)alloc((size_t)BATCH * UDIM * 4);
    float* hBF  = (float*)alloc((size_t)BATCH * UDIM * 4);
    short* hAH  = (short*)alloc((size_t)BATCH * UDIM * 2);
    short* hAL  = (short*)alloc((size_t)BATCH * UDIM * 2);
    short* hBH  = (short*)alloc((size_t)BATCH * UDIM * 2);
    short* hBL  = (short*)alloc((size_t)BATCH * UDIM * 2);
    float* tmp2 = (float*)alloc((size_t)BATCH * UDIM * 4);
    short* gxHi = (short*)alloc((size_t)BATCH * GXW * 2);
    short* gxLo = (short*)alloc((size_t)BATCH * GXW * 2);
    short* encAHi = (short*)alloc((size_t)BATCH * SLEN * UDIM * 2);
    short* encALo = (short*)alloc((size_t)BATCH * SLEN * UDIM * 2);
    float* encProjF = (float*)alloc((size_t)BATCH * SLEN * UDIM * 4);
    short* eWihH = (short*)alloc((size_t)U3 * VIND * 2);
    short* eWihL = (short*)alloc((size_t)U3 * VIND * 2);
    short* eWrH = (short*)alloc((size_t)UDIM * UDIM * 2);
    short* eWrL = (short*)alloc((size_t)UDIM * UDIM * 2);
    short* eWzH = (short*)alloc((size_t)UDIM * UDIM * 2);
    short* eWzL = (short*)alloc((size_t)UDIM * UDIM * 2);
    short* eWnH = (short*)alloc((size_t)UDIM * UDIM * 2);
    short* eWnL = (short*)alloc((size_t)UDIM * UDIM * 2);
    short* dWrH = (short*)alloc((size_t)UDIM * 2560 * 2);
    short* dWrL = (short*)alloc((size_t)UDIM * 2560 * 2);
    short* dWzH = (short*)alloc((size_t)UDIM * 2560 * 2);
    short* dWzL = (short*)alloc((size_t)UDIM * 2560 * 2);
    short* dWnhH = (short*)alloc((size_t)UDIM * UDIM * 2);
    short* dWnhL = (short*)alloc((size_t)UDIM * UDIM * 2);
    short* dWniH = (short*)alloc((size_t)UDIM * GXW * 2);
    short* dWniL = (short*)alloc((size_t)UDIM * GXW * 2);
    short* w1Hi = (short*)alloc((size_t)UDIM * UDIM * 2);
    short* w1Lo = (short*)alloc((size_t)UDIM * UDIM * 2);
    short* w2Hi = (short*)alloc((size_t)UDIM * UDIM * 2);
    short* w2Lo = (short*)alloc((size_t)UDIM * UDIM * 2);
    short* fcHi = (short*)alloc((size_t)VOUTD * UDIM * 2);
    short* fcLo = (short*)alloc((size_t)VOUTD * UDIM * 2);
    short* xHi  = (short*)alloc((size_t)SLEN * BATCH * VIND * 2);
    short* xLo  = (short*)alloc((size_t)SLEN * BATCH * VIND * 2);
    int*   idx  = (int*)alloc(BATCH * 4);
    float* o2hT = (float*)alloc((size_t)VOUTD * EDIM * 4);

    init_kernel<<<(BATCH * UDIM + 255) / 256, 256, 0, stream>>>(
        hAF, hAH, hAL, out, idx, o2h_W, o2h_b, o2hT);

    // ---- single packing kernel for all weights + x ----
    {
        PackArgs pa;
        int cs = 0, n = 0;
        auto seg = [&](const float* sA, int KA, int offA, const float* sB, int KB,
                       int offB, short* Hi, short* Lo, int R) {
            pa.s[n] = {sA, sB, Hi, Lo, KA, KB, offA, offB, cs};
            cs += R * (KA + KB) / 8;
            n++;
        };
        seg(enc_Wih, VIND, 0, nullptr, 0, 0, eWihH, eWihL, U3);
        seg(enc_Whh, UDIM, 0, nullptr, 0, 0, eWrH, eWrL, UDIM);
        seg(enc_Whh, UDIM, UDIM, nullptr, 0, 0, eWzH, eWzL, UDIM);
        seg(enc_Whh, UDIM, 2 * UDIM, nullptr, 0, 0, eWnH, eWnL, UDIM);
        seg(dec_Whh, UDIM, 0, dec_Wih, GXW, 0, dWrH, dWrL, UDIM);
        seg(dec_Whh, UDIM, UDIM, dec_Wih, GXW, UDIM, dWzH, dWzL, UDIM);
        seg(dec_Whh, UDIM, 2 * UDIM, nullptr, 0, 0, dWnhH, dWnhL, UDIM);
        seg(dec_Wih, GXW, 2 * UDIM, nullptr, 0, 0, dWniH, dWniL, UDIM);
        seg(W1_W, UDIM, 0, nullptr, 0, 0, w1Hi, w1Lo, UDIM);
        seg(W2_W, UDIM, 0, nullptr, 0, 0, w2Hi, w2Lo, UDIM);
        seg(fc_W, UDIM, 0, nullptr, 0, 0, fcHi, fcLo, VOUTD);
        seg(x, VIND, 0, nullptr, 0, 0, xHi, xLo, SLEN * BATCH);
        pack_all<<<(cs + 255) / 256, 256, 0, stream>>>(pa, cs);
    }

    // ---- encoder: 64 fused GRU steps (gi computed in-kernel from x) ----
    float* hcF = hAF; float* hnF = hBF;
    short *hcH = hAH, *hcL = hAL, *hnH = hBH, *hnL = hBL;
    for (int t = 0; t < SLEN; t++) {
        enc_gru3<<<dim3(64, 4), 768, 0, stream>>>(
            (const short8*)hcH, (const short8*)hcL,
            (const short8*)xHi, (const short8*)xLo,
            (const short8*)eWihH, (const short8*)eWihL,
            (const short8*)eWrH, (const short8*)eWrL,
            (const short8*)eWzH, (const short8*)eWzL,
            (const short8*)eWnH, (const short8*)eWnL,
            enc_bih, enc_bhh, hcF, hnF, hnH, hnL,
            encAHi, encALo, x_len, t);
        { float* tf = hcF; hcF = hnF; hnF = tf; }
        { short* th = hcH; hcH = hnH; hnH = th; th = hcL; hcL = hnL; hnL = th; }
    }

    // ---- enc_proj = enc_out @ W1^T + W1_b ----
    gemm_w<<<dim3(SLEN * BATCH / 64, UDIM / 128), 256, 0, stream>>>(
        (const short8*)encAHi, (const short8*)encALo,
        (const short8*)w1Hi, (const short8*)w1Lo,
        W1_b, encProjF, UDIM / 32, UDIM);

    // ---- initial tmp2 from encoder hidden ----
    gemm_bm32<<<dim3(BATCH / 32, UDIM / 64), 256, 0, stream>>>(
        (const short8*)hcH, (const short8*)hcL,
        (const short8*)w2Hi, (const short8*)w2Lo,
        W2_b, tmp2, UDIM / 32, UDIM);

    // ---- greedy decode: 24 steps x 3 dispatches ----
    for (int st = 0; st < TDEC - 1; st++) {
        attn_ctx<<<BATCH, 1024, 0, stream>>>(
            encProjF, encAHi, encALo, tmp2, V_W, V_b, o2hT, idx, gxHi, gxLo);
        dec_gru3<<<dim3(64, 4), 768, 0, stream>>>(
            (const short8*)hcH, (const short8*)hcL,
            (const short8*)gxHi, (const short8*)gxLo,
            (const short8*)dWrH, (const short8*)dWrL,
            (const short8*)dWzH, (const short8*)dWzL,
            (const short8*)dWnhH, (const short8*)dWnhL,
            (const short8*)dWniH, (const short8*)dWniL,
            dec_bih, dec_bhh, hcF, hnF, hnH, hnL);
        float* pred = out + (size_t)(1 + st) * BATCH * VOUTD;
        int nblk = (st == TDEC - 2) ? 16 : 144;   // last step: tmp2 dead
        fcw2<<<nblk, 256, 0, stream>>>(
            (const short8*)hnH, (const short8*)hnL,
            (const short8*)fcHi, (const short8*)fcLo,
            fc_b, pred, idx,
            (const short8*)w2Hi, (const short8*)w2Lo, W2_b, tmp2);
        { float* tf = hcF; hcF = hnF; hnF = tf; }
        { short* th = hcH; hcH = hnH; hnH = th; th = hcL; hcL = hnL; hnL = th; }
    }
}